// Round 9
// baseline (1872.604 us; speedup 1.0000x reference)
//
#include <hip/hip_runtime.h>
#include <hip/hip_bf16.h>

#define DEVINL __device__ __forceinline__

typedef float f32x4 __attribute__((ext_vector_type(4)));
typedef unsigned short u16x8 __attribute__((ext_vector_type(8)));
typedef __bf16 bf16x8 __attribute__((ext_vector_type(8)));

static constexpr int NN = 40000;     // nodes
static constexpr int NE = 640000;    // edges (divisible by 256)
static constexpr int H  = 128;
static constexpr int NSCAN = 40;     // ceil(NN/1024)

// ---- ws layout (bytes) ----
static constexpr long O_HACC = 0;                       // f32 [NN][128]
static constexpr long O_H16  = 20480000;                // bf16 [NN][128]
static constexpr long O_DEG  = 30720000;                // f32 [NN] (deg_inv)
static constexpr long O_WP   = 30880000;                // prepped weights 18*32KB
static constexpr long O_HDP  = 31600896;                // bf16 [NN][128] sigma-permuted
static constexpr long O_HSP  = 41840896;                // bf16 [NN][128] sigma-permuted
static constexpr long O_CNT  = 52080896;                // u32 [NN]
static constexpr long O_LOC  = 52240896;                // u32 [NN]
static constexpr long O_ROWP = 52400896;                // u32 [NN+1] (+pad)
static constexpr long O_CURS = 52560912;                // u32 [NN]
static constexpr long O_BSUM = 52720912;                // u32 [64]
static constexpr long O_PERM = 52721168;                // u32 [NE]
static constexpr long O_SRCS = 55281168;                // i32 [NE]
static constexpr long O_DSTS = 57841168;                // i32 [NE]
static constexpr long O_T16  = 60401168;                // bf16 [NE][128] (m, sigma cols)
static constexpr long O_EA16 = 224241168;               // bf16 [NE][128] sorted
static constexpr long NEED_T1 = O_EA16;                 // 224.2 MB
static constexpr long NEED_T2 = O_EA16 + (long)NE * H * 2;  // 388.1 MB

// prepped-weight blocks (16384 ushorts each):
// m0 e2n_W1(A)  m1 e2n_W2(K)  m2..10 {W1a,W1b,W1c}(A) per layer
// m11..13 W2(K) per layer     m14..16 nW(A)  m17 outW1(A)
__host__ __device__ inline const unsigned short* wpm(const unsigned short* wp, int m) {
  return wp + m * 16384;
}

DEVINL unsigned short f2bf(float f) {
  unsigned int u = __float_as_uint(f);
  u += 0x7fffu + ((u >> 16) & 1u);     // round-to-nearest-even
  return (unsigned short)(u >> 16);
}
DEVINL float bf2f(unsigned short u) {
  return __uint_as_float(((unsigned int)u) << 16);
}

DEVINL f32x4 mfma16(u16x8 a, u16x8 b, f32x4 c) {
  return __builtin_amdgcn_mfma_f32_16x16x32_bf16(
      __builtin_bit_cast(bf16x8, a), __builtin_bit_cast(bf16x8, b), c, 0, 0, 0);
}

// ---------------- weight prep ----------------
// mode A: Wp[((ks*8+nb)*64+l)*8+j] = W[32ks + 8*(l>>4) + j][16nb + (l&15)]
// mode K: Wp[...]                  = W[4ks + (l>>4) + 16j][16nb + (l&15)]
struct PrepPtrs { const float* p[18]; };

__global__ void prep_all(PrepPtrs pp, unsigned short* __restrict__ wp) {
  constexpr int MODE[18] = {0,1, 0,0,0, 0,0,0, 0,0,0, 1,1,1, 0,0,0, 0};
  int m = blockIdx.y;
  int idx = blockIdx.x * 256 + threadIdx.x;
  if (idx >= 16384) return;
  int j  = idx & 7, l = (idx >> 3) & 63, nb = (idx >> 9) & 7, ks = idx >> 12;
  int hi = l >> 4, lo = l & 15;
  int k = MODE[m] ? (4*ks + hi + 16*j) : (32*ks + 8*hi + j);
  int n = nb*16 + lo;
  wp[m * 16384 + idx] = f2bf(pp.p[m][k*128 + n]);
}

// ---------------- counting sort by dst ----------------
__global__ void hist_k(const int* __restrict__ dst, unsigned* __restrict__ cnt) {
  int e = blockIdx.x * 256 + threadIdx.x;
  atomicAdd(&cnt[dst[e]], 1u);
}

__global__ void scan1_k(const unsigned* __restrict__ cnt, unsigned* __restrict__ loc,
                        unsigned* __restrict__ bsum) {
  __shared__ unsigned sh[256];
  int t = threadIdx.x;
  int base = blockIdx.x * 1024 + t * 4;
  unsigned v[4]; unsigned s = 0;
  #pragma unroll
  for (int j = 0; j < 4; ++j) {
    v[j] = (base + j < NN) ? cnt[base + j] : 0u;
    s += v[j];
  }
  sh[t] = s; __syncthreads();
  #pragma unroll
  for (int off = 1; off < 256; off <<= 1) {
    unsigned y = (t >= off) ? sh[t - off] : 0u;
    __syncthreads();
    sh[t] += y;
    __syncthreads();
  }
  unsigned run = sh[t] - s;   // exclusive base for this thread
  #pragma unroll
  for (int j = 0; j < 4; ++j) {
    if (base + j < NN) loc[base + j] = run;
    run += v[j];
  }
  if (t == 255) bsum[blockIdx.x] = sh[255];
}

__global__ void scan2_k(unsigned* __restrict__ bsum) {
  int t = threadIdx.x;   // 64 threads, one wave
  unsigned orig = (t < NSCAN) ? bsum[t] : 0u;
  unsigned v = orig;
  #pragma unroll
  for (int off = 1; off < 64; off <<= 1) {
    unsigned y = __shfl_up(v, off);
    if (t >= off) v += y;
  }
  if (t < NSCAN) bsum[t] = v - orig;   // exclusive
}

__global__ void scan3_k(const unsigned* __restrict__ loc, const unsigned* __restrict__ bsum,
                        const unsigned* __restrict__ cnt, unsigned* __restrict__ rowPtr,
                        unsigned* __restrict__ cursor, float* __restrict__ deg_inv) {
  int i = blockIdx.x * 256 + threadIdx.x;
  if (i < NN) {
    unsigned r = loc[i] + bsum[i >> 10];
    rowPtr[i] = r;
    cursor[i] = r;
    deg_inv[i] = 1.0f / fmaxf((float)cnt[i], 1.0f);
  }
  if (i == NN) rowPtr[NN] = (unsigned)NE;
}

__global__ void scat_k(const int* __restrict__ src, const int* __restrict__ dst,
                       unsigned* __restrict__ cursor, unsigned* __restrict__ perm,
                       int* __restrict__ srcS, int* __restrict__ dstS) {
  int e = blockIdx.x * 256 + threadIdx.x;
  int d = dst[e];
  unsigned pos = atomicAdd(&cursor[d], 1u);
  perm[pos] = (unsigned)e;
  srcS[pos] = src[e];
  dstS[pos] = d;
}

// ---------------- h0 convert ----------------
__global__ void cvt_h0(const float* __restrict__ src, unsigned short* __restrict__ dst) {
  long i = ((long)blockIdx.x * 256 + threadIdx.x) * 8;
  f32x4 a = *(const f32x4*)(src + i);
  f32x4 b = *(const f32x4*)(src + i + 4);
  u16x8 t;
  #pragma unroll
  for (int j = 0; j < 4; ++j) { t[j] = f2bf(a[j]); t[4+j] = f2bf(b[j]); }
  *(u16x8*)(dst + i) = t;
}

// ---------------- node transform: Hdp = h@W1a, Hsp = h@W1b (sigma-permuted) ----------------
__global__ __launch_bounds__(256) void node_xform(
    const unsigned short* __restrict__ h16,
    const unsigned short* __restrict__ wpa, const unsigned short* __restrict__ wpb,
    unsigned short* __restrict__ Hdp, unsigned short* __restrict__ Hsp) {
  const int tid = threadIdx.x;
  const int wave = tid >> 6, lane = tid & 63;
  const int hi = lane >> 4, lo = lane & 15;
  const int n0w = blockIdx.x * 256 + wave * 64;

  #pragma unroll
  for (int out = 0; out < 2; ++out) {
    const unsigned short* wp = out ? wpb : wpa;
    unsigned short* dp = out ? Hsp : Hdp;
    f32x4 acc[4][8];
    #pragma unroll
    for (int mf = 0; mf < 4; ++mf)
      #pragma unroll
      for (int nb = 0; nb < 8; ++nb) acc[mf][nb] = (f32x4)(0.0f);
    #pragma unroll
    for (int s = 0; s < 4; ++s) {
      u16x8 a[4];
      #pragma unroll
      for (int mf = 0; mf < 4; ++mf) {
        int n = n0w + 16 * mf + lo; if (n >= NN) n = NN - 1;
        a[mf] = *(const u16x8*)(h16 + (long)n * 128 + s * 32 + hi * 8);
      }
      #pragma unroll
      for (int nb = 0; nb < 8; ++nb) {
        u16x8 b = *(const u16x8*)(wp + ((s * 8 + nb) * 64 + lane) * 8);
        #pragma unroll
        for (int mf = 0; mf < 4; ++mf) acc[mf][nb] = mfma16(a[mf], b, acc[mf][nb]);
      }
    }
    #pragma unroll
    for (int mf = 0; mf < 4; ++mf)
      #pragma unroll
      for (int r = 0; r < 4; ++r) {
        int n = n0w + 16 * mf + 4 * hi + r;
        if (n < NN) {
          u16x8 pack;
          #pragma unroll
          for (int nb = 0; nb < 8; ++nb) pack[nb] = f2bf(acc[mf][nb][r]);
          *(u16x8*)(dp + (long)n * 128 + 8 * lo) = pack;   // sigma: col 16nb+lo -> 8lo+nb
        }
      }
  }
}

// ---------------- K12 (fused, sorted edges, TLP version) ----------------
// m16 = (relu(ea@W1 [+Hd[dst]+Hs[src]] + b1))@W2 + b2   (sigma cols)
// W1/W2 fragments read from GLOBAL (identical across waves -> L1/L2 resident).
// LDS = 16KB wave-private stripes only; ZERO barriers; 6 blocks/CU target.
// EAM: 0 = gather ea32 via perm (EAST: also store ea16 sorted), 1 = read ea16 sorted.
template<int EAM, bool EAST, bool GATH>
__global__ __launch_bounds__(256, 6) void k12_pass(
    const float* __restrict__ ea32, unsigned short* __restrict__ ea16,
    const unsigned* __restrict__ perm,
    const unsigned short* __restrict__ w1p, const unsigned short* __restrict__ w2p,
    const float* __restrict__ b1, const float* __restrict__ b2,
    const unsigned short* __restrict__ Hdp, const unsigned short* __restrict__ Hsp,
    const int* __restrict__ srcS, const int* __restrict__ dstS,
    unsigned short* __restrict__ m16) {
  __shared__ char smem[16384];   // 4 wave-private stripes
  const int tid = threadIdx.x;
  const int wave = tid >> 6, lane = tid & 63;
  const int hi = lane >> 4, lo = lane & 15;

  // bijective XCD swizzle: contiguous dst-chunk per XCD
  const int nwg = gridDim.x;
  const int xcd = blockIdx.x & 7, base = blockIdx.x >> 3;
  const int qc = nwg >> 3, rc = nwg & 7;
  const int bid = (xcd < rc ? xcd * (qc + 1) : rc * (qc + 1) + (xcd - rc) * qc) + base;
  const long e0w = (long)bid * 256 + wave * 64;
  char* sstripe = smem + wave * 4096;

  unsigned pId[4];
  int dId[4], sId[4];
  #pragma unroll
  for (int mf = 0; mf < 4; ++mf) {
    if (EAM == 0) pId[mf] = perm[e0w + 16 * mf + lo];
    if (GATH) {
      dId[mf] = dstS[e0w + 16 * mf + lo];
      sId[mf] = srcS[e0w + 16 * mf + lo];
    }
  }

  float b1v[8], b2v[8];
  #pragma unroll
  for (int nb = 0; nb < 8; ++nb) { b1v[nb] = b1[nb * 16 + lo]; b2v[nb] = b2[nb * 16 + lo]; }

  auto loadEA = [&](int mf, u16x8 (&v)[4]) {
    #pragma unroll
    for (int s = 0; s < 4; ++s) {
      if (EAM == 1) {
        v[s] = *(const u16x8*)(ea16 + (e0w + 16 * mf + lo) * 128 + s * 32 + hi * 8);
      } else {
        long eoff = (long)pId[mf] * 128 + s * 32 + hi * 8;
        f32x4 f0 = *(const f32x4*)(ea32 + eoff);
        f32x4 f1 = *(const f32x4*)(ea32 + eoff + 4);
        u16x8 t;
        #pragma unroll
        for (int j = 0; j < 4; ++j) { t[j] = f2bf(f0[j]); t[4+j] = f2bf(f1[j]); }
        if (EAST) *(u16x8*)(ea16 + (e0w + 16 * mf + lo) * 128 + s * 32 + hi * 8) = t;
        v[s] = t;
      }
    }
  };
  auto loadG = [&](int mf, u16x8 (&gd)[4], u16x8 (&gs)[4]) {
    #pragma unroll
    for (int r = 0; r < 4; ++r) {
      int rd = __shfl(dId[mf], 4 * hi + r);
      int rs = __shfl(sId[mf], 4 * hi + r);
      gd[r] = *(const u16x8*)(Hdp + (long)rd * 128 + 8 * lo);
      gs[r] = *(const u16x8*)(Hsp + (long)rs * 128 + 8 * lo);
    }
  };

  const int er2 = lane >> 2, q = lane & 3;

  #pragma unroll
  for (int mf = 0; mf < 4; ++mf) {
    u16x8 ea[4], gd[4], gs[4];
    loadEA(mf, ea);
    if (GATH) loadG(mf, gd, gs);

    // ---- GEMM1 (acc starts at 0; gathers added after) ----
    f32x4 acc[8];
    #pragma unroll
    for (int nb = 0; nb < 8; ++nb) acc[nb] = (f32x4)(0.0f);
    #pragma unroll
    for (int s = 0; s < 4; ++s)
      #pragma unroll
      for (int nb = 0; nb < 8; ++nb) {
        u16x8 b = *(const u16x8*)(w1p + ((s * 8 + nb) * 64 + lane) * 8);
        acc[nb] = mfma16(ea[s], b, acc[nb]);
      }
    if (GATH) {
      #pragma unroll
      for (int nb = 0; nb < 8; ++nb)
        #pragma unroll
        for (int r = 0; r < 4; ++r)
          acc[nb][r] += bf2f(gd[r][nb]) + bf2f(gs[r][nb]);
    }

    // ---- epilogue1: bias+relu -> bf16 -> sigma stripe ----
    #pragma unroll
    for (int r = 0; r < 4; ++r) {
      int er = 4 * hi + r;
      u16x8 pack;
      #pragma unroll
      for (int nb = 0; nb < 8; ++nb)
        pack[nb] = f2bf(fmaxf(acc[nb][r] + b1v[nb], 0.0f));
      *(u16x8*)(sstripe + er * 256 + ((lo * 16) ^ ((er & 7) << 4))) = pack;
    }

    // ---- GEMM2 (wave-private stripe, no barrier) ----
    f32x4 acc2[8];
    #pragma unroll
    for (int nb = 0; nb < 8; ++nb) acc2[nb] = (f32x4)(0.0f);
    #pragma unroll
    for (int s2 = 0; s2 < 4; ++s2) {
      u16x8 a = *(const u16x8*)(sstripe + lo * 256 +
                                (((4 * s2 + hi) * 16) ^ ((lo & 7) << 4)));
      #pragma unroll
      for (int nb = 0; nb < 8; ++nb) {
        u16x8 b = *(const u16x8*)(w2p + ((s2 * 8 + nb) * 64 + lane) * 8);
        acc2[nb] = mfma16(a, b, acc2[nb]);
      }
    }

    // ---- epilogue2: +bias -> bf16 -> stripe -> m16 (full-sector stores) ----
    #pragma unroll
    for (int r = 0; r < 4; ++r) {
      int er = 4 * hi + r;
      u16x8 pack;
      #pragma unroll
      for (int nb = 0; nb < 8; ++nb)
        pack[nb] = f2bf(acc2[nb][r] + b2v[nb]);
      *(u16x8*)(sstripe + er * 256 + ((lo * 16) ^ ((er & 7) << 4))) = pack;
    }
    #pragma unroll
    for (int i = 0; i < 4; ++i) {
      int c = i * 4 + q;   // lanes q=0..3 -> contiguous 64B
      u16x8 v = *(const u16x8*)(sstripe + er2 * 256 + ((c * 16) ^ ((er2 & 7) << 4)));
      *(u16x8*)(m16 + (e0w + 16 * mf + er2) * 128 + c * 8) = v;
    }
  }
}

// ---------------- segment sum: hacc[n] = (1/deg?) * sum_{q in [rowPtr[n],rowPtr[n+1])} m16[q] ----
// m16 cols sigma-permuted (pos p holds col 16*(p&7)+(p>>3)); de-sigma on write.
template<bool SCALE>
__global__ __launch_bounds__(256) void segsum_k(
    const unsigned short* __restrict__ m16, const unsigned* __restrict__ rowPtr,
    const float* __restrict__ deg_inv, float* __restrict__ hacc) {
  int n = blockIdx.x * 16 + (threadIdx.x >> 4);
  int c = threadIdx.x & 15;
  if (n >= NN) return;
  unsigned q0 = rowPtr[n], q1 = rowPtr[n + 1];
  float s[8];
  #pragma unroll
  for (int j = 0; j < 8; ++j) s[j] = 0.0f;
  for (unsigned q = q0; q < q1; ++q) {
    u16x8 v = *(const u16x8*)(m16 + (long)q * 128 + c * 8);
    #pragma unroll
    for (int j = 0; j < 8; ++j) s[j] += bf2f(v[j]);
  }
  float scl = SCALE ? deg_inv[n] : 1.0f;
  #pragma unroll
  for (int j = 0; j < 8; ++j)
    hacc[(long)n * 128 + j * 16 + c] = s[j] * scl;   // pos 8c+j -> col 16j+c
}

// ---------------- fused fallback (tier0, atomics) ----------------
template<int NSRC>
__global__ __launch_bounds__(256, 4) void edge_fused(
    const unsigned short* __restrict__ h16, const float* __restrict__ ea32,
    const unsigned short* __restrict__ w1p, const unsigned short* __restrict__ w2p,
    const float* __restrict__ b1, const float* __restrict__ b2,
    const int* __restrict__ srcIds, const int* __restrict__ dstIds,
    const float* __restrict__ deg_inv, float* __restrict__ target) {
  __shared__ char smem[16384];
  const int tid = threadIdx.x;
  const int wave = tid >> 6, lane = tid & 63;
  const int hi = lane >> 4, lo = lane & 15;
  const int e0w = blockIdx.x * 128 + wave * 32;
  constexpr int KS1 = NSRC * 4;
  char* sstripe = smem + wave * 4096;

  int dId[2]; float dScl[2];
  const unsigned short* pd[2]; const unsigned short* ps[2];
  #pragma unroll
  for (int mf = 0; mf < 2; ++mf) {
    dId[mf] = dstIds[e0w + 16 * mf + lo];
    if (NSRC == 3) {
      int s_ = srcIds[e0w + 16 * mf + lo];
      pd[mf] = h16 + (long)dId[mf] * 128;
      ps[mf] = h16 + (long)s_ * 128;
      dScl[mf] = deg_inv[dId[mf]];
    }
  }
  f32x4 acc[2][8];
  #pragma unroll
  for (int mf = 0; mf < 2; ++mf)
    #pragma unroll
    for (int nb = 0; nb < 8; ++nb) acc[mf][nb] = (f32x4)(0.0f);

  auto loadA = [&](int s, u16x8 (&v)[2]) {
    #pragma unroll
    for (int mf = 0; mf < 2; ++mf) {
      if (NSRC == 3 && s < 8) {
        const unsigned short* base = (s < 4) ? pd[mf] : ps[mf];
        v[mf] = *(const u16x8*)(base + (s & 3) * 32 + hi * 8);
      } else {
        long eoff = (long)(e0w + 16 * mf + lo) * 128 + (s & 3) * 32 + hi * 8;
        f32x4 f0 = *(const f32x4*)(ea32 + eoff);
        f32x4 f1 = *(const f32x4*)(ea32 + eoff + 4);
        u16x8 t;
        #pragma unroll
        for (int j = 0; j < 4; ++j) { t[j] = f2bf(f0[j]); t[4+j] = f2bf(f1[j]); }
        v[mf] = t;
      }
    }
  };

  u16x8 aA[2], aB[2];
  loadA(0, aA);
  auto g1body = [&](int s, u16x8 (&cur)[2], u16x8 (&nxt)[2]) {
    if (s + 1 < KS1) loadA(s + 1, nxt);
    #pragma unroll
    for (int nb = 0; nb < 8; ++nb) {
      u16x8 b = *(const u16x8*)(w1p + ((s * 8 + nb) * 64 + lane) * 8);
      acc[0][nb] = mfma16(cur[0], b, acc[0][nb]);
      acc[1][nb] = mfma16(cur[1], b, acc[1][nb]);
    }
  };
  #pragma unroll
  for (int sp = 0; sp < KS1; sp += 2) { g1body(sp, aA, aB); g1body(sp + 1, aB, aA); }

  float b1v[8], b2v[8];
  #pragma unroll
  for (int nb = 0; nb < 8; ++nb) { b1v[nb] = b1[nb*16 + lo]; b2v[nb] = b2[nb*16 + lo]; }

  #pragma unroll
  for (int mf = 0; mf < 2; ++mf) {
    #pragma unroll
    for (int r = 0; r < 4; ++r) {
      int er = 4 * hi + r;
      u16x8 pack;
      #pragma unroll
      for (int nb = 0; nb < 8; ++nb)
        pack[nb] = f2bf(fmaxf(acc[mf][nb][r] + b1v[nb], 0.0f));
      *(u16x8*)(sstripe + er * 256 + ((lo * 16) ^ ((er & 7) << 4))) = pack;
    }
    #pragma unroll
    for (int nb = 0; nb < 8; ++nb) acc[mf][nb] = (f32x4)(0.0f);
    #pragma unroll
    for (int s2 = 0; s2 < 4; ++s2) {
      u16x8 a = *(const u16x8*)(sstripe + lo * 256 +
                                (((4 * s2 + hi) * 16) ^ ((lo & 7) << 4)));
      #pragma unroll
      for (int nb = 0; nb < 8; ++nb) {
        u16x8 b = *(const u16x8*)(w2p + ((s2 * 8 + nb) * 64 + lane) * 8);
        acc[mf][nb] = mfma16(a, b, acc[mf][nb]);
      }
    }
    int eR[4]; float sc[4];
    #pragma unroll
    for (int r = 0; r < 4; ++r) {
      eR[r] = __shfl(dId[mf], 4 * hi + r);
      sc[r] = (NSRC == 3) ? __shfl(dScl[mf], 4 * hi + r) : 1.0f;
    }
    #pragma unroll
    for (int nb = 0; nb < 8; ++nb)
      #pragma unroll
      for (int r = 0; r < 4; ++r) {
        float v = (acc[mf][nb][r] + b2v[nb]) * sc[r];
        unsafeAtomicAdd(&target[(long)eR[r] * 128 + nb * 16 + lo], v);
      }
  }
}

// ---------------- node MLP: h16 = relu(agg @ Wn + bn) ----------------
__global__ __launch_bounds__(256) void node_pass(
    const float* __restrict__ agg, const unsigned short* __restrict__ wp,
    const float* __restrict__ bias, unsigned short* __restrict__ h16out) {
  __shared__ char smem[49152];
  const int tid = threadIdx.x;
  const int wave = tid >> 6, lane = tid & 63;
  const int hi = lane >> 4, lo = lane & 15;
  const int n0 = blockIdx.x * 64;
  const int r = tid >> 2, q = tid & 3;

  #pragma unroll
  for (int s = 0; s < 4; ++s) {
    f32x4 f0 = *(const f32x4*)(agg + (long)(n0 + r) * 128 + s * 32 + q * 8);
    f32x4 f1 = *(const f32x4*)(agg + (long)(n0 + r) * 128 + s * 32 + q * 8 + 4);
    u16x8 t;
    #pragma unroll
    for (int j = 0; j < 4; ++j) { t[j] = f2bf(f0[j]); t[4+j] = f2bf(f1[j]); }
    *(u16x8*)(smem + s * 4096 + (((r >> 4) * 64 + q * 16 + (r & 15)) << 4)) = t;
  }
  {
    const u16x8* g = (const u16x8*)wp;
    u16x8* l = (u16x8*)(smem + 16384);
    #pragma unroll
    for (int i = 0; i < 8; ++i) l[i * 256 + tid] = g[i * 256 + tid];
  }
  __syncthreads();

  f32x4 acc[8];
  #pragma unroll
  for (int nb = 0; nb < 8; ++nb) acc[nb] = (f32x4)(0.0f);
  #pragma unroll
  for (int s = 0; s < 4; ++s) {
    u16x8 a = *(const u16x8*)(smem + s * 4096 + wave * 1024 + (lane << 4));
    #pragma unroll
    for (int nb = 0; nb < 8; ++nb) {
      u16x8 b = *(const u16x8*)(smem + 16384 + ((s * 8 + nb) << 10) + (lane << 4));
      acc[nb] = mfma16(a, b, acc[nb]);
    }
  }
  float bv[8];
  #pragma unroll
  for (int nb = 0; nb < 8; ++nb) bv[nb] = bias[nb * 16 + lo];
  #pragma unroll
  for (int nb = 0; nb < 8; ++nb)
    #pragma unroll
    for (int rr = 0; rr < 4; ++rr) {
      int node = n0 + 16 * wave + 4 * hi + rr;
      float v = fmaxf(acc[nb][rr] + bv[nb], 0.0f);
      h16out[(long)node * 128 + nb * 16 + lo] = f2bf(v);
    }
}

// ---------------- output head ----------------
__global__ __launch_bounds__(256) void out_pass(
    const unsigned short* __restrict__ h16, const unsigned short* __restrict__ wp,
    const float* __restrict__ ob1, const float* __restrict__ oW2,
    const float* __restrict__ ob2, float* __restrict__ out) {
  __shared__ char smem[49152];
  const int tid = threadIdx.x;
  const int wave = tid >> 6, lane = tid & 63;
  const int hi = lane >> 4, lo = lane & 15;
  const int n0 = blockIdx.x * 64;
  const int r = tid >> 2, q = tid & 3;

  #pragma unroll
  for (int s = 0; s < 4; ++s) {
    u16x8 t = *(const u16x8*)(h16 + (long)(n0 + r) * 128 + s * 32 + q * 8);
    *(u16x8*)(smem + s * 4096 + (((r >> 4) * 64 + q * 16 + (r & 15)) << 4)) = t;
  }
  {
    const u16x8* g = (const u16x8*)wp;
    u16x8* l = (u16x8*)(smem + 16384);
    #pragma unroll
    for (int i = 0; i < 8; ++i) l[i * 256 + tid] = g[i * 256 + tid];
  }
  __syncthreads();

  f32x4 acc[8];
  #pragma unroll
  for (int nb = 0; nb < 8; ++nb) acc[nb] = (f32x4)(0.0f);
  #pragma unroll
  for (int s = 0; s < 4; ++s) {
    u16x8 a = *(const u16x8*)(smem + s * 4096 + wave * 1024 + (lane << 4));
    #pragma unroll
    for (int nb = 0; nb < 8; ++nb) {
      u16x8 b = *(const u16x8*)(smem + 16384 + ((s * 8 + nb) << 10) + (lane << 4));
      acc[nb] = mfma16(a, b, acc[nb]);
    }
  }
  float b1v[8], w2v[8][3];
  #pragma unroll
  for (int nb = 0; nb < 8; ++nb) {
    b1v[nb] = ob1[nb * 16 + lo];
    #pragma unroll
    for (int o = 0; o < 3; ++o) w2v[nb][o] = oW2[(nb * 16 + lo) * 3 + o];
  }
  #pragma unroll
  for (int rr = 0; rr < 4; ++rr) {
    float p0 = 0.f, p1 = 0.f, p2 = 0.f;
    #pragma unroll
    for (int nb = 0; nb < 8; ++nb) {
      float t = fmaxf(acc[nb][rr] + b1v[nb], 0.0f);
      p0 += t * w2v[nb][0]; p1 += t * w2v[nb][1]; p2 += t * w2v[nb][2];
    }
    #pragma unroll
    for (int off = 1; off < 16; off <<= 1) {
      p0 += __shfl_xor(p0, off); p1 += __shfl_xor(p1, off); p2 += __shfl_xor(p2, off);
    }
    if (lo == 0) {
      int node = n0 + 16 * wave + 4 * hi + rr;
      out[(long)node * 3 + 0] = p0 + ob2[0];
      out[(long)node * 3 + 1] = p1 + ob2[1];
      out[(long)node * 3 + 2] = p2 + ob2[2];
    }
  }
}

// ---------------- host ----------------
extern "C" void kernel_launch(void* const* d_in, const int* in_sizes, int n_in,
                              void* d_out, int out_size, void* d_ws, size_t ws_size,
                              hipStream_t stream) {
  const int*   ei     = (const int*)d_in[1];
  const int*   srcIds = ei;
  const int*   dstIds = ei + NE;
  const float* ea     = (const float*)d_in[2];
  const float* e2nb1  = (const float*)d_in[4];
  const float* e2nb2  = (const float*)d_in[6];
  const float* eW1    = (const float*)d_in[7];
  const float* eb1    = (const float*)d_in[8];
  const float* eW2    = (const float*)d_in[9];
  const float* eb2    = (const float*)d_in[10];
  const float* nW     = (const float*)d_in[11];
  const float* nb_    = (const float*)d_in[12];
  const float* ob1    = (const float*)d_in[14];
  const float* oW2    = (const float*)d_in[15];
  const float* ob2    = (const float*)d_in[16];
  float* out = (float*)d_out;

  char* ws = (char*)d_ws;
  float* hacc = (float*)(ws + O_HACC);
  unsigned short* h16 = (unsigned short*)(ws + O_H16);
  float* deg_inv = (float*)(ws + O_DEG);
  unsigned short* wp = (unsigned short*)(ws + O_WP);
  unsigned short* Hdp = (unsigned short*)(ws + O_HDP);
  unsigned short* Hsp = (unsigned short*)(ws + O_HSP);
  unsigned* cnt    = (unsigned*)(ws + O_CNT);
  unsigned* loc    = (unsigned*)(ws + O_LOC);
  unsigned* rowPtr = (unsigned*)(ws + O_ROWP);
  unsigned* cursor = (unsigned*)(ws + O_CURS);
  unsigned* bsum   = (unsigned*)(ws + O_BSUM);
  unsigned* perm   = (unsigned*)(ws + O_PERM);
  int* srcS        = (int*)(ws + O_SRCS);
  int* dstS        = (int*)(ws + O_DSTS);
  unsigned short* t16 = (unsigned short*)(ws + O_T16);
  unsigned short* ea16 = (unsigned short*)(ws + O_EA16);
  const bool tier2 = ws_size >= (size_t)NEED_T2;
  const bool tier1 = ws_size >= (size_t)NEED_T1;

  PrepPtrs pp;
  pp.p[0] = (const float*)d_in[3];
  pp.p[1] = (const float*)d_in[5];
  for (int l = 0; l < 3; ++l) {
    pp.p[2 + 3*l] = eW1 + l * 49152;             // W1a
    pp.p[3 + 3*l] = eW1 + l * 49152 + 16384;     // W1b
    pp.p[4 + 3*l] = eW1 + l * 49152 + 32768;     // W1c
    pp.p[11 + l]  = eW2 + l * 16384;             // W2 (kappa)
    pp.p[14 + l]  = nW  + l * 16384;             // nW
  }
  pp.p[17] = (const float*)d_in[13];

  prep_all<<<dim3(64, 18), 256, 0, stream>>>(pp, wp);

  // counting sort by dst + deg_inv
  hipMemsetAsync(cnt, 0, (size_t)NN * 4, stream);
  hist_k<<<NE / 256, 256, 0, stream>>>(dstIds, cnt);
  scan1_k<<<NSCAN, 256, 0, stream>>>(cnt, loc, bsum);
  scan2_k<<<1, 64, 0, stream>>>(bsum);
  scan3_k<<<(NN + 256) / 256, 256, 0, stream>>>(loc, bsum, cnt, rowPtr, cursor, deg_inv);
  scat_k<<<NE / 256, 256, 0, stream>>>(srcIds, dstIds, cursor, perm, srcS, dstS);

  if (tier1) {
    // ---- e2n ----
    if (tier2)
      k12_pass<0, true, false><<<NE / 256, 256, 0, stream>>>(
          ea, ea16, perm, wpm(wp, 0), wpm(wp, 1), e2nb1, e2nb2,
          nullptr, nullptr, srcS, dstS, t16);
    else
      k12_pass<0, false, false><<<NE / 256, 256, 0, stream>>>(
          ea, nullptr, perm, wpm(wp, 0), wpm(wp, 1), e2nb1, e2nb2,
          nullptr, nullptr, srcS, dstS, t16);
    segsum_k<false><<<(NN + 15) / 16, 256, 0, stream>>>(t16, rowPtr, nullptr, hacc);
    cvt_h0<<<NN * H / (256 * 8), 256, 0, stream>>>(hacc, h16);

    for (int l = 0; l < 3; ++l) {
      node_xform<<<(NN + 255) / 256, 256, 0, stream>>>(
          h16, wpm(wp, 2 + 3*l), wpm(wp, 3 + 3*l), Hdp, Hsp);
      if (tier2)
        k12_pass<1, false, true><<<NE / 256, 256, 0, stream>>>(
            ea, ea16, perm, wpm(wp, 4 + 3*l), wpm(wp, 11 + l),
            eb1 + l * 128, eb2 + l * 128, Hdp, Hsp, srcS, dstS, t16);
      else
        k12_pass<0, false, true><<<NE / 256, 256, 0, stream>>>(
            ea, nullptr, perm, wpm(wp, 4 + 3*l), wpm(wp, 11 + l),
            eb1 + l * 128, eb2 + l * 128, Hdp, Hsp, srcS, dstS, t16);
      segsum_k<true><<<(NN + 15) / 16, 256, 0, stream>>>(t16, rowPtr, deg_inv, hacc);
      node_pass<<<NN / 64, 256, 0, stream>>>(hacc, wpm(wp, 14 + l),
                                             nb_ + l * 128, h16);
    }
  } else {
    // ---- tier0 fused fallback (atomics) ----
    hipMemsetAsync(hacc, 0, (size_t)NN * H * 4, stream);
    edge_fused<1><<<NE / 128, 256, 0, stream>>>(
        h16, ea, wpm(wp, 0), wpm(wp, 1), e2nb1, e2nb2, srcIds, dstIds, nullptr, hacc);
    cvt_h0<<<NN * H / (256 * 8), 256, 0, stream>>>(hacc, h16);
    for (int l = 0; l < 3; ++l) {
      hipMemsetAsync(hacc, 0, (size_t)NN * H * 4, stream);
      edge_fused<3><<<NE / 128, 256, 0, stream>>>(
          h16, ea, wpm(wp, 2 + 3*l), wpm(wp, 11 + l), eb1 + l * 128, eb2 + l * 128,
          srcIds, dstIds, deg_inv, hacc);
      node_pass<<<NN / 64, 256, 0, stream>>>(hacc, wpm(wp, 14 + l),
                                             nb_ + l * 128, h16);
    }
  }

  out_pass<<<NN / 64, 256, 0, stream>>>(h16, wpm(wp, 17), ob1, oW2, ob2, out);
}

// Round 10
// 809.638 us; speedup vs baseline: 2.3129x; 2.3129x over previous
//
#include <hip/hip_runtime.h>
#include <hip/hip_bf16.h>

#define DEVINL __device__ __forceinline__

typedef float f32x4 __attribute__((ext_vector_type(4)));
typedef unsigned short u16x8 __attribute__((ext_vector_type(8)));
typedef __bf16 bf16x8 __attribute__((ext_vector_type(8)));

static constexpr int NN = 40000;     // nodes
static constexpr int NE = 640000;    // edges (divisible by 256)
static constexpr int H  = 128;
static constexpr int NSCAN = 40;     // ceil(NN/1024)

// ---- ws layout (bytes) ----
static constexpr long O_HACC = 0;                       // f32 [NN][128]
static constexpr long O_H16  = 20480000;                // bf16 [NN][128]
static constexpr long O_DEG  = 30720000;                // f32 [NN] (deg_inv)
static constexpr long O_WP   = 30880000;                // prepped weights 18*32KB
static constexpr long O_HDP  = 31600896;                // bf16 [NN][128] sigma-permuted
static constexpr long O_HSP  = 41840896;                // bf16 [NN][128] sigma-permuted
static constexpr long O_CNT  = 52080896;                // u32 [NN]
static constexpr long O_LOC  = 52240896;                // u32 [NN]
static constexpr long O_ROWP = 52400896;                // u32 [NN+1] (+pad)
static constexpr long O_CURS = 52560912;                // u32 [NN]
static constexpr long O_BSUM = 52720912;                // u32 [64]
static constexpr long O_PERM = 52721168;                // u32 [NE]
static constexpr long O_SRCS = 55281168;                // i32 [NE]
static constexpr long O_DSTS = 57841168;                // i32 [NE]
static constexpr long O_T16  = 60401168;                // bf16 [NE][128] (m, sigma cols)
static constexpr long O_EA16 = 224241168;               // bf16 [NE][128] sorted
static constexpr long NEED_T1 = O_EA16;                 // 224.2 MB
static constexpr long NEED_T2 = O_EA16 + (long)NE * H * 2;  // 388.1 MB

// prepped-weight blocks (16384 ushorts each):
// m0 e2n_W1(A)  m1 e2n_W2(K)  m2..10 {W1a,W1b,W1c}(A) per layer
// m11..13 W2(K) per layer     m14..16 nW(A)  m17 outW1(A)
__host__ __device__ inline const unsigned short* wpm(const unsigned short* wp, int m) {
  return wp + m * 16384;
}

DEVINL unsigned short f2bf(float f) {
  unsigned int u = __float_as_uint(f);
  u += 0x7fffu + ((u >> 16) & 1u);     // round-to-nearest-even
  return (unsigned short)(u >> 16);
}
DEVINL float bf2f(unsigned short u) {
  return __uint_as_float(((unsigned int)u) << 16);
}

DEVINL f32x4 mfma16(u16x8 a, u16x8 b, f32x4 c) {
  return __builtin_amdgcn_mfma_f32_16x16x32_bf16(
      __builtin_bit_cast(bf16x8, a), __builtin_bit_cast(bf16x8, b), c, 0, 0, 0);
}

// ---------------- weight prep ----------------
// mode A: Wp[((ks*8+nb)*64+l)*8+j] = W[32ks + 8*(l>>4) + j][16nb + (l&15)]
// mode K: Wp[...]                  = W[4ks + (l>>4) + 16j][16nb + (l&15)]
struct PrepPtrs { const float* p[18]; };

__global__ void prep_all(PrepPtrs pp, unsigned short* __restrict__ wp) {
  constexpr int MODE[18] = {0,1, 0,0,0, 0,0,0, 0,0,0, 1,1,1, 0,0,0, 0};
  int m = blockIdx.y;
  int idx = blockIdx.x * 256 + threadIdx.x;
  if (idx >= 16384) return;
  int j  = idx & 7, l = (idx >> 3) & 63, nb = (idx >> 9) & 7, ks = idx >> 12;
  int hi = l >> 4, lo = l & 15;
  int k = MODE[m] ? (4*ks + hi + 16*j) : (32*ks + 8*hi + j);
  int n = nb*16 + lo;
  wp[m * 16384 + idx] = f2bf(pp.p[m][k*128 + n]);
}

// ---------------- counting sort by dst ----------------
__global__ void hist_k(const int* __restrict__ dst, unsigned* __restrict__ cnt) {
  int e = blockIdx.x * 256 + threadIdx.x;
  atomicAdd(&cnt[dst[e]], 1u);
}

__global__ void scan1_k(const unsigned* __restrict__ cnt, unsigned* __restrict__ loc,
                        unsigned* __restrict__ bsum) {
  __shared__ unsigned sh[256];
  int t = threadIdx.x;
  int base = blockIdx.x * 1024 + t * 4;
  unsigned v[4]; unsigned s = 0;
  #pragma unroll
  for (int j = 0; j < 4; ++j) {
    v[j] = (base + j < NN) ? cnt[base + j] : 0u;
    s += v[j];
  }
  sh[t] = s; __syncthreads();
  #pragma unroll
  for (int off = 1; off < 256; off <<= 1) {
    unsigned y = (t >= off) ? sh[t - off] : 0u;
    __syncthreads();
    sh[t] += y;
    __syncthreads();
  }
  unsigned run = sh[t] - s;   // exclusive base for this thread
  #pragma unroll
  for (int j = 0; j < 4; ++j) {
    if (base + j < NN) loc[base + j] = run;
    run += v[j];
  }
  if (t == 255) bsum[blockIdx.x] = sh[255];
}

__global__ void scan2_k(unsigned* __restrict__ bsum) {
  int t = threadIdx.x;   // 64 threads, one wave
  unsigned orig = (t < NSCAN) ? bsum[t] : 0u;
  unsigned v = orig;
  #pragma unroll
  for (int off = 1; off < 64; off <<= 1) {
    unsigned y = __shfl_up(v, off);
    if (t >= off) v += y;
  }
  if (t < NSCAN) bsum[t] = v - orig;   // exclusive
}

__global__ void scan3_k(const unsigned* __restrict__ loc, const unsigned* __restrict__ bsum,
                        const unsigned* __restrict__ cnt, unsigned* __restrict__ rowPtr,
                        unsigned* __restrict__ cursor, float* __restrict__ deg_inv) {
  int i = blockIdx.x * 256 + threadIdx.x;
  if (i < NN) {
    unsigned r = loc[i] + bsum[i >> 10];
    rowPtr[i] = r;
    cursor[i] = r;
    deg_inv[i] = 1.0f / fmaxf((float)cnt[i], 1.0f);
  }
  if (i == NN) rowPtr[NN] = (unsigned)NE;
}

__global__ void scat_k(const int* __restrict__ src, const int* __restrict__ dst,
                       unsigned* __restrict__ cursor, unsigned* __restrict__ perm,
                       int* __restrict__ srcS, int* __restrict__ dstS) {
  int e = blockIdx.x * 256 + threadIdx.x;
  int d = dst[e];
  unsigned pos = atomicAdd(&cursor[d], 1u);
  perm[pos] = (unsigned)e;
  srcS[pos] = src[e];
  dstS[pos] = d;
}

// ---------------- h0 convert ----------------
__global__ void cvt_h0(const float* __restrict__ src, unsigned short* __restrict__ dst) {
  long i = ((long)blockIdx.x * 256 + threadIdx.x) * 8;
  f32x4 a = *(const f32x4*)(src + i);
  f32x4 b = *(const f32x4*)(src + i + 4);
  u16x8 t;
  #pragma unroll
  for (int j = 0; j < 4; ++j) { t[j] = f2bf(a[j]); t[4+j] = f2bf(b[j]); }
  *(u16x8*)(dst + i) = t;
}

// ---------------- node transform: Hdp = h@W1a, Hsp = h@W1b (sigma-permuted) ----------------
__global__ __launch_bounds__(256) void node_xform(
    const unsigned short* __restrict__ h16,
    const unsigned short* __restrict__ wpa, const unsigned short* __restrict__ wpb,
    unsigned short* __restrict__ Hdp, unsigned short* __restrict__ Hsp) {
  const int tid = threadIdx.x;
  const int wave = tid >> 6, lane = tid & 63;
  const int hi = lane >> 4, lo = lane & 15;
  const int n0w = blockIdx.x * 256 + wave * 64;

  #pragma unroll
  for (int out = 0; out < 2; ++out) {
    const unsigned short* wp = out ? wpb : wpa;
    unsigned short* dp = out ? Hsp : Hdp;
    f32x4 acc[4][8];
    #pragma unroll
    for (int mf = 0; mf < 4; ++mf)
      #pragma unroll
      for (int nb = 0; nb < 8; ++nb) acc[mf][nb] = (f32x4)(0.0f);
    #pragma unroll
    for (int s = 0; s < 4; ++s) {
      u16x8 a[4];
      #pragma unroll
      for (int mf = 0; mf < 4; ++mf) {
        int n = n0w + 16 * mf + lo; if (n >= NN) n = NN - 1;
        a[mf] = *(const u16x8*)(h16 + (long)n * 128 + s * 32 + hi * 8);
      }
      #pragma unroll
      for (int nb = 0; nb < 8; ++nb) {
        u16x8 b = *(const u16x8*)(wp + ((s * 8 + nb) * 64 + lane) * 8);
        #pragma unroll
        for (int mf = 0; mf < 4; ++mf) acc[mf][nb] = mfma16(a[mf], b, acc[mf][nb]);
      }
    }
    #pragma unroll
    for (int mf = 0; mf < 4; ++mf)
      #pragma unroll
      for (int r = 0; r < 4; ++r) {
        int n = n0w + 16 * mf + 4 * hi + r;
        if (n < NN) {
          u16x8 pack;
          #pragma unroll
          for (int nb = 0; nb < 8; ++nb) pack[nb] = f2bf(acc[mf][nb][r]);
          *(u16x8*)(dp + (long)n * 128 + 8 * lo) = pack;   // sigma: col 16nb+lo -> 8lo+nb
        }
      }
  }
}

// ---------------- K12 (fused, sorted edges, asm-forced load pipeline) ----------------
// m16 = (relu(ea@W1 [+Hd[dst]+Hs[src]] + b1))@W2 + b2   (sigma cols)
// Weights LDS-resident (R9 showed global weights thrash HBM: +157MB FETCH).
// Operand loads issued via asm volatile global_load_dwordx4 (unsinkable) one
// mf-tile ahead; compute gated by counted s_waitcnt vmcnt(N) with "+v" ties.
// N = loads(mf+1) [+ stores(mf-1)] — exact FIFO arithmetic, never 0 mid-loop.
// LDS (dynamic 81920): [0,32K) W1; [32K,64K) W2; [64K,80K) 4 wave-stripes.
template<int EAM, bool EAST, bool GATH>
__global__ __launch_bounds__(256, 2) void k12_pass(
    const float* __restrict__ ea32, unsigned short* __restrict__ ea16,
    const unsigned* __restrict__ perm,
    const unsigned short* __restrict__ w1p, const unsigned short* __restrict__ w2p,
    const float* __restrict__ b1, const float* __restrict__ b2,
    const unsigned short* __restrict__ Hdp, const unsigned short* __restrict__ Hsp,
    const int* __restrict__ srcS, const int* __restrict__ dstS,
    unsigned short* __restrict__ m16) {
  extern __shared__ char smem[];
  const int tid = threadIdx.x;
  const int wave = tid >> 6, lane = tid & 63;
  const int hi = lane >> 4, lo = lane & 15;

  // bijective XCD swizzle: contiguous dst-chunk per XCD
  const int nwg = gridDim.x;
  const int xcd = blockIdx.x & 7, bbase = blockIdx.x >> 3;
  const int qc = nwg >> 3, rc = nwg & 7;
  const int bid = (xcd < rc ? xcd * (qc + 1) : rc * (qc + 1) + (xcd - rc) * qc) + bbase;
  const long e0w = (long)bid * 256 + wave * 64;
  char* sstripe = smem + 65536 + wave * 4096;

  constexpr int LB = (EAM == 0 ? 8 : 4) + (GATH ? 8 : 0);   // asm loads / batch
  constexpr int SB = 4 + (EAST ? 4 : 0);                    // stores / iter

  unsigned pId[4];
  int dId[4], sId[4];
  #pragma unroll
  for (int mf = 0; mf < 4; ++mf) {
    if (EAM == 0) pId[mf] = perm[e0w + 16 * mf + lo];
    if (GATH) {
      dId[mf] = dstS[e0w + 16 * mf + lo];
      sId[mf] = srcS[e0w + 16 * mf + lo];
    }
  }

  float b1v[8], b2v[8];
  #pragma unroll
  for (int nb = 0; nb < 8; ++nb) { b1v[nb] = b1[nb * 16 + lo]; b2v[nb] = b2[nb * 16 + lo]; }

  // double-buffered operand sets (asm outputs — tied at the waits, can't be sunk)
  u16x8 eaA[4], eaB[4], gdA[4], gsA[4], gdB[4], gsB[4];
  f32x4 efA[8], efB[8];

  auto issue = [&](int mf, u16x8 (&ea)[4], f32x4 (&ef)[8],
                   u16x8 (&gd)[4], u16x8 (&gs)[4]) {
    if (EAM == 1) {
      #pragma unroll
      for (int s = 0; s < 4; ++s) {
        const unsigned short* p = ea16 + (e0w + 16 * mf + lo) * 128 + s * 32 + hi * 8;
        asm volatile("global_load_dwordx4 %0, %1, off" : "=&v"(ea[s]) : "v"(p) : "memory");
      }
    } else {
      #pragma unroll
      for (int s = 0; s < 4; ++s) {
        const float* p = ea32 + (long)pId[mf] * 128 + s * 32 + hi * 8;
        asm volatile("global_load_dwordx4 %0, %1, off" : "=&v"(ef[2*s])   : "v"(p)     : "memory");
        asm volatile("global_load_dwordx4 %0, %1, off" : "=&v"(ef[2*s+1]) : "v"(p + 4) : "memory");
      }
    }
    if (GATH) {
      #pragma unroll
      for (int r = 0; r < 4; ++r) {
        int rd = __shfl(dId[mf], 4 * hi + r);
        int rs = __shfl(sId[mf], 4 * hi + r);
        const unsigned short* pd = Hdp + (long)rd * 128 + 8 * lo;
        const unsigned short* ps = Hsp + (long)rs * 128 + 8 * lo;
        asm volatile("global_load_dwordx4 %0, %1, off" : "=&v"(gd[r]) : "v"(pd) : "memory");
        asm volatile("global_load_dwordx4 %0, %1, off" : "=&v"(gs[r]) : "v"(ps) : "memory");
      }
    }
  };

  issue(0, eaA, efA, gdA, gsA);   // batch0 lands under weight staging + barrier

  { // stage W1 + W2 into LDS (once)
    const u16x8* g1 = (const u16x8*)w1p;
    u16x8* l1 = (u16x8*)smem;
    #pragma unroll
    for (int i = 0; i < 8; ++i) l1[i * 256 + tid] = g1[i * 256 + tid];
    const u16x8* g2 = (const u16x8*)w2p;
    u16x8* l2 = (u16x8*)(smem + 32768);
    #pragma unroll
    for (int i = 0; i < 8; ++i) l2[i * 256 + tid] = g2[i * 256 + tid];
  }
  __syncthreads();

  const int er2 = lane >> 2, q = lane & 3;

  #pragma unroll
  for (int mf = 0; mf < 4; ++mf) {
    u16x8 (&ea)[4] = (mf & 1) ? eaB : eaA;
    f32x4 (&ef)[8] = (mf & 1) ? efB : efA;
    u16x8 (&gd)[4] = (mf & 1) ? gdB : gdA;
    u16x8 (&gs)[4] = (mf & 1) ? gsB : gsA;
    if (mf < 3)
      issue(mf + 1, (mf & 1) ? eaA : eaB, (mf & 1) ? efA : efB,
            (mf & 1) ? gdA : gdB, (mf & 1) ? gsA : gsB);

    // gate on batch(mf); newer ops = loads(mf+1) + stores(mf-1)
    if (EAM == 1) {
      if (GATH) {
        asm volatile("s_waitcnt vmcnt(%12)"
          : "+v"(ea[0]), "+v"(ea[1]), "+v"(ea[2]), "+v"(ea[3]),
            "+v"(gd[0]), "+v"(gd[1]), "+v"(gd[2]), "+v"(gd[3]),
            "+v"(gs[0]), "+v"(gs[1]), "+v"(gs[2]), "+v"(gs[3])
          : "n"((mf < 3 ? LB : 0) + (mf > 0 ? SB : 0)));
      } else {
        asm volatile("s_waitcnt vmcnt(%4)"
          : "+v"(ea[0]), "+v"(ea[1]), "+v"(ea[2]), "+v"(ea[3])
          : "n"((mf < 3 ? LB : 0) + (mf > 0 ? SB : 0)));
      }
    } else if (GATH) {
      asm volatile("s_waitcnt vmcnt(%16)"
        : "+v"(ef[0]), "+v"(ef[1]), "+v"(ef[2]), "+v"(ef[3]),
          "+v"(ef[4]), "+v"(ef[5]), "+v"(ef[6]), "+v"(ef[7]),
          "+v"(gd[0]), "+v"(gd[1]), "+v"(gd[2]), "+v"(gd[3]),
          "+v"(gs[0]), "+v"(gs[1]), "+v"(gs[2]), "+v"(gs[3])
        : "n"((mf < 3 ? LB : 0) + (mf > 0 ? SB : 0)));
    } else {
      asm volatile("s_waitcnt vmcnt(%8)"
        : "+v"(ef[0]), "+v"(ef[1]), "+v"(ef[2]), "+v"(ef[3]),
          "+v"(ef[4]), "+v"(ef[5]), "+v"(ef[6]), "+v"(ef[7])
        : "n"((mf < 3 ? LB : 0) + (mf > 0 ? SB : 0)));
    }

    if (EAM == 0) {   // convert f32 -> bf16 (and optionally store sorted ea16)
      #pragma unroll
      for (int s = 0; s < 4; ++s) {
        u16x8 t;
        #pragma unroll
        for (int j = 0; j < 4; ++j) { t[j] = f2bf(ef[2*s][j]); t[4+j] = f2bf(ef[2*s+1][j]); }
        if (EAST)
          *(u16x8*)(ea16 + (e0w + 16 * mf + lo) * 128 + s * 32 + hi * 8) = t;
        ea[s] = t;
      }
    }

    // ---- GEMM1 (acc starts at 0; gathers added after) ----
    f32x4 acc[8];
    #pragma unroll
    for (int nb = 0; nb < 8; ++nb) acc[nb] = (f32x4)(0.0f);
    #pragma unroll
    for (int s = 0; s < 4; ++s)
      #pragma unroll
      for (int nb = 0; nb < 8; ++nb) {
        u16x8 b = *(const u16x8*)(smem + ((s * 8 + nb) << 10) + (lane << 4));
        acc[nb] = mfma16(ea[s], b, acc[nb]);
      }
    if (GATH) {
      #pragma unroll
      for (int nb = 0; nb < 8; ++nb)
        #pragma unroll
        for (int r = 0; r < 4; ++r)
          acc[nb][r] += bf2f(gd[r][nb]) + bf2f(gs[r][nb]);
    }

    // ---- epilogue1: bias+relu -> bf16 -> sigma stripe ----
    #pragma unroll
    for (int r = 0; r < 4; ++r) {
      int er = 4 * hi + r;
      u16x8 pack;
      #pragma unroll
      for (int nb = 0; nb < 8; ++nb)
        pack[nb] = f2bf(fmaxf(acc[nb][r] + b1v[nb], 0.0f));
      *(u16x8*)(sstripe + er * 256 + ((lo * 16) ^ ((er & 7) << 4))) = pack;
    }

    // ---- GEMM2 (wave-private stripe, no barrier) ----
    f32x4 acc2[8];
    #pragma unroll
    for (int nb = 0; nb < 8; ++nb) acc2[nb] = (f32x4)(0.0f);
    #pragma unroll
    for (int s2 = 0; s2 < 4; ++s2) {
      u16x8 a = *(const u16x8*)(sstripe + lo * 256 +
                                (((4 * s2 + hi) * 16) ^ ((lo & 7) << 4)));
      #pragma unroll
      for (int nb = 0; nb < 8; ++nb) {
        u16x8 b = *(const u16x8*)(smem + 32768 + ((s2 * 8 + nb) << 10) + (lane << 4));
        acc2[nb] = mfma16(a, b, acc2[nb]);
      }
    }

    // ---- epilogue2: +bias -> bf16 -> stripe -> m16 (full-sector stores) ----
    #pragma unroll
    for (int r = 0; r < 4; ++r) {
      int er = 4 * hi + r;
      u16x8 pack;
      #pragma unroll
      for (int nb = 0; nb < 8; ++nb)
        pack[nb] = f2bf(acc2[nb][r] + b2v[nb]);
      *(u16x8*)(sstripe + er * 256 + ((lo * 16) ^ ((er & 7) << 4))) = pack;
    }
    #pragma unroll
    for (int i = 0; i < 4; ++i) {
      int c = i * 4 + q;   // lanes q=0..3 -> contiguous 64B
      u16x8 v = *(const u16x8*)(sstripe + er2 * 256 + ((c * 16) ^ ((er2 & 7) << 4)));
      *(u16x8*)(m16 + (e0w + 16 * mf + er2) * 128 + c * 8) = v;
    }
  }
}

// ---------------- segment sum: hacc[n] = (1/deg?) * sum_{q in [rowPtr[n],rowPtr[n+1])} m16[q] ----
// m16 cols sigma-permuted (pos p holds col 16*(p&7)+(p>>3)); de-sigma on write.
template<bool SCALE>
__global__ __launch_bounds__(256) void segsum_k(
    const unsigned short* __restrict__ m16, const unsigned* __restrict__ rowPtr,
    const float* __restrict__ deg_inv, float* __restrict__ hacc) {
  int n = blockIdx.x * 16 + (threadIdx.x >> 4);
  int c = threadIdx.x & 15;
  if (n >= NN) return;
  unsigned q0 = rowPtr[n], q1 = rowPtr[n + 1];
  float s[8];
  #pragma unroll
  for (int j = 0; j < 8; ++j) s[j] = 0.0f;
  for (unsigned q = q0; q < q1; ++q) {
    u16x8 v = *(const u16x8*)(m16 + (long)q * 128 + c * 8);
    #pragma unroll
    for (int j = 0; j < 8; ++j) s[j] += bf2f(v[j]);
  }
  float scl = SCALE ? deg_inv[n] : 1.0f;
  #pragma unroll
  for (int j = 0; j < 8; ++j)
    hacc[(long)n * 128 + j * 16 + c] = s[j] * scl;   // pos 8c+j -> col 16j+c
}

// ---------------- node MLP: h16 = relu(agg @ Wn + bn) ----------------
__global__ __launch_bounds__(256) void node_pass(
    const float* __restrict__ agg, const unsigned short* __restrict__ wp,
    const float* __restrict__ bias, unsigned short* __restrict__ h16out) {
  __shared__ char smem[49152];
  const int tid = threadIdx.x;
  const int wave = tid >> 6, lane = tid & 63;
  const int hi = lane >> 4, lo = lane & 15;
  const int n0 = blockIdx.x * 64;
  const int r = tid >> 2, q = tid & 3;

  #pragma unroll
  for (int s = 0; s < 4; ++s) {
    f32x4 f0 = *(const f32x4*)(agg + (long)(n0 + r) * 128 + s * 32 + q * 8);
    f32x4 f1 = *(const f32x4*)(agg + (long)(n0 + r) * 128 + s * 32 + q * 8 + 4);
    u16x8 t;
    #pragma unroll
    for (int j = 0; j < 4; ++j) { t[j] = f2bf(f0[j]); t[4+j] = f2bf(f1[j]); }
    *(u16x8*)(smem + s * 4096 + (((r >> 4) * 64 + q * 16 + (r & 15)) << 4)) = t;
  }
  {
    const u16x8* g = (const u16x8*)wp;
    u16x8* l = (u16x8*)(smem + 16384);
    #pragma unroll
    for (int i = 0; i < 8; ++i) l[i * 256 + tid] = g[i * 256 + tid];
  }
  __syncthreads();

  f32x4 acc[8];
  #pragma unroll
  for (int nb = 0; nb < 8; ++nb) acc[nb] = (f32x4)(0.0f);
  #pragma unroll
  for (int s = 0; s < 4; ++s) {
    u16x8 a = *(const u16x8*)(smem + s * 4096 + wave * 1024 + (lane << 4));
    #pragma unroll
    for (int nb = 0; nb < 8; ++nb) {
      u16x8 b = *(const u16x8*)(smem + 16384 + ((s * 8 + nb) << 10) + (lane << 4));
      acc[nb] = mfma16(a, b, acc[nb]);
    }
  }
  float bv[8];
  #pragma unroll
  for (int nb = 0; nb < 8; ++nb) bv[nb] = bias[nb * 16 + lo];
  #pragma unroll
  for (int nb = 0; nb < 8; ++nb)
    #pragma unroll
    for (int rr = 0; rr < 4; ++rr) {
      int node = n0 + 16 * wave + 4 * hi + rr;
      float v = fmaxf(acc[nb][rr] + bv[nb], 0.0f);
      h16out[(long)node * 128 + nb * 16 + lo] = f2bf(v);
    }
}

// ---------------- output head ----------------
__global__ __launch_bounds__(256) void out_pass(
    const unsigned short* __restrict__ h16, const unsigned short* __restrict__ wp,
    const float* __restrict__ ob1, const float* __restrict__ oW2,
    const float* __restrict__ ob2, float* __restrict__ out) {
  __shared__ char smem[49152];
  const int tid = threadIdx.x;
  const int wave = tid >> 6, lane = tid & 63;
  const int hi = lane >> 4, lo = lane & 15;
  const int n0 = blockIdx.x * 64;
  const int r = tid >> 2, q = tid & 3;

  #pragma unroll
  for (int s = 0; s < 4; ++s) {
    u16x8 t = *(const u16x8*)(h16 + (long)(n0 + r) * 128 + s * 32 + q * 8);
    *(u16x8*)(smem + s * 4096 + (((r >> 4) * 64 + q * 16 + (r & 15)) << 4)) = t;
  }
  {
    const u16x8* g = (const u16x8*)wp;
    u16x8* l = (u16x8*)(smem + 16384);
    #pragma unroll
    for (int i = 0; i < 8; ++i) l[i * 256 + tid] = g[i * 256 + tid];
  }
  __syncthreads();

  f32x4 acc[8];
  #pragma unroll
  for (int nb = 0; nb < 8; ++nb) acc[nb] = (f32x4)(0.0f);
  #pragma unroll
  for (int s = 0; s < 4; ++s) {
    u16x8 a = *(const u16x8*)(smem + s * 4096 + wave * 1024 + (lane << 4));
    #pragma unroll
    for (int nb = 0; nb < 8; ++nb) {
      u16x8 b = *(const u16x8*)(smem + 16384 + ((s * 8 + nb) << 10) + (lane << 4));
      acc[nb] = mfma16(a, b, acc[nb]);
    }
  }
  float b1v[8], w2v[8][3];
  #pragma unroll
  for (int nb = 0; nb < 8; ++nb) {
    b1v[nb] = ob1[nb * 16 + lo];
    #pragma unroll
    for (int o = 0; o < 3; ++o) w2v[nb][o] = oW2[(nb * 16 + lo) * 3 + o];
  }
  #pragma unroll
  for (int rr = 0; rr < 4; ++rr) {
    float p0 = 0.f, p1 = 0.f, p2 = 0.f;
    #pragma unroll
    for (int nb = 0; nb < 8; ++nb) {
      float t = fmaxf(acc[nb][rr] + b1v[nb], 0.0f);
      p0 += t * w2v[nb][0]; p1 += t * w2v[nb][1]; p2 += t * w2v[nb][2];
    }
    #pragma unroll
    for (int off = 1; off < 16; off <<= 1) {
      p0 += __shfl_xor(p0, off); p1 += __shfl_xor(p1, off); p2 += __shfl_xor(p2, off);
    }
    if (lo == 0) {
      int node = n0 + 16 * wave + 4 * hi + rr;
      out[(long)node * 3 + 0] = p0 + ob2[0];
      out[(long)node * 3 + 1] = p1 + ob2[1];
      out[(long)node * 3 + 2] = p2 + ob2[2];
    }
  }
}

// ---------------- host ----------------
extern "C" void kernel_launch(void* const* d_in, const int* in_sizes, int n_in,
                              void* d_out, int out_size, void* d_ws, size_t ws_size,
                              hipStream_t stream) {
  const int*   ei     = (const int*)d_in[1];
  const int*   srcIds = ei;
  const int*   dstIds = ei + NE;
  const float* ea     = (const float*)d_in[2];
  const float* e2nb1  = (const float*)d_in[4];
  const float* e2nb2  = (const float*)d_in[6];
  const float* eW1    = (const float*)d_in[7];
  const float* eb1    = (const float*)d_in[8];
  const float* eW2    = (const float*)d_in[9];
  const float* eb2    = (const float*)d_in[10];
  const float* nW     = (const float*)d_in[11];
  const float* nb_    = (const float*)d_in[12];
  const float* ob1    = (const float*)d_in[14];
  const float* oW2    = (const float*)d_in[15];
  const float* ob2    = (const float*)d_in[16];
  float* out = (float*)d_out;

  char* ws = (char*)d_ws;
  float* hacc = (float*)(ws + O_HACC);
  unsigned short* h16 = (unsigned short*)(ws + O_H16);
  float* deg_inv = (float*)(ws + O_DEG);
  unsigned short* wp = (unsigned short*)(ws + O_WP);
  unsigned short* Hdp = (unsigned short*)(ws + O_HDP);
  unsigned short* Hsp = (unsigned short*)(ws + O_HSP);
  unsigned* cnt    = (unsigned*)(ws + O_CNT);
  unsigned* loc    = (unsigned*)(ws + O_LOC);
  unsigned* rowPtr = (unsigned*)(ws + O_ROWP);
  unsigned* cursor = (unsigned*)(ws + O_CURS);
  unsigned* bsum   = (unsigned*)(ws + O_BSUM);
  unsigned* perm   = (unsigned*)(ws + O_PERM);
  int* srcS        = (int*)(ws + O_SRCS);
  int* dstS        = (int*)(ws + O_DSTS);
  unsigned short* t16 = (unsigned short*)(ws + O_T16);
  unsigned short* ea16 = (unsigned short*)(ws + O_EA16);
  const bool tier2 = ws_size >= (size_t)NEED_T2;
  const bool tier1 = ws_size >= (size_t)NEED_T1;

  PrepPtrs pp;
  pp.p[0] = (const float*)d_in[3];
  pp.p[1] = (const float*)d_in[5];
  for (int l = 0; l < 3; ++l) {
    pp.p[2 + 3*l] = eW1 + l * 49152;             // W1a
    pp.p[3 + 3*l] = eW1 + l * 49152 + 16384;     // W1b
    pp.p[4 + 3*l] = eW1 + l * 49152 + 32768;     // W1c
    pp.p[11 + l]  = eW2 + l * 16384;             // W2 (kappa)
    pp.p[14 + l]  = nW  + l * 16384;             // nW
  }
  pp.p[17] = (const float*)d_in[13];

  prep_all<<<dim3(64, 18), 256, 0, stream>>>(pp, wp);

  // counting sort by dst + deg_inv
  hipMemsetAsync(cnt, 0, (size_t)NN * 4, stream);
  hist_k<<<NE / 256, 256, 0, stream>>>(dstIds, cnt);
  scan1_k<<<NSCAN, 256, 0, stream>>>(cnt, loc, bsum);
  scan2_k<<<1, 64, 0, stream>>>(bsum);
  scan3_k<<<(NN + 256) / 256, 256, 0, stream>>>(loc, bsum, cnt, rowPtr, cursor, deg_inv);
  scat_k<<<NE / 256, 256, 0, stream>>>(srcIds, dstIds, cursor, perm, srcS, dstS);

  if (tier1) {
    // ---- e2n ----
    if (tier2)
      k12_pass<0, true, false><<<NE / 256, 256, 81920, stream>>>(
          ea, ea16, perm, wpm(wp, 0), wpm(wp, 1), e2nb1, e2nb2,
          nullptr, nullptr, srcS, dstS, t16);
    else
      k12_pass<0, false, false><<<NE / 256, 256, 81920, stream>>>(
          ea, nullptr, perm, wpm(wp, 0), wpm(wp, 1), e2nb1, e2nb2,
          nullptr, nullptr, srcS, dstS, t16);
    segsum_k<false><<<(NN + 15) / 16, 256, 0, stream>>>(t16, rowPtr, nullptr, hacc);
    cvt_h0<<<NN * H / (256 * 8), 256, 0, stream>>>(hacc, h16);

    for (int l = 0; l < 3; ++l) {
      node_xform<<<(NN + 255) / 256, 256, 0, stream>>>(
          h16, wpm(wp, 2 + 3*l), wpm(wp, 3 + 3*l), Hdp, Hsp);
      if (tier2)
        k12_pass<1, false, true><<<NE / 256, 256, 81920, stream>>>(
            ea, ea16, perm, wpm(wp, 4 + 3*l), wpm(wp, 11 + l),
            eb1 + l * 128, eb2 + l * 128, Hdp, Hsp, srcS, dstS, t16);
      else
        k12_pass<0, false, true><<<NE / 256, 256, 81920, stream>>>(
            ea, nullptr, perm, wpm(wp, 4 + 3*l), wpm(wp, 11 + l),
            eb1 + l * 128, eb2 + l * 128, Hdp, Hsp, srcS, dstS, t16);
      segsum_k<true><<<(NN + 15) / 16, 256, 0, stream>>>(t16, rowPtr, deg_inv, hacc);
      node_pass<<<NN / 64, 256, 0, stream>>>(hacc, wpm(wp, 14 + l),
                                             nb_ + l * 128, h16);
    }
  } else {
    // ---- tier0 fallback: k12 with in-place perm gather, no ea16 cache ----
    hipMemsetAsync(hacc, 0, (size_t)NN * H * 4, stream);
    k12_pass<0, false, false><<<NE / 256, 256, 81920, stream>>>(
        ea, nullptr, perm, wpm(wp, 0), wpm(wp, 1), e2nb1, e2nb2,
        nullptr, nullptr, srcS, dstS, t16);
    segsum_k<false><<<(NN + 15) / 16, 256, 0, stream>>>(t16, rowPtr, nullptr, hacc);
    cvt_h0<<<NN * H / (256 * 8), 256, 0, stream>>>(hacc, h16);
    for (int l = 0; l < 3; ++l) {
      node_xform<<<(NN + 255) / 256, 256, 0, stream>>>(
          h16, wpm(wp, 2 + 3*l), wpm(wp, 3 + 3*l), Hdp, Hsp);
      k12_pass<0, false, true><<<NE / 256, 256, 81920, stream>>>(
          ea, nullptr, perm, wpm(wp, 4 + 3*l), wpm(wp, 11 + l),
          eb1 + l * 128, eb2 + l * 128, Hdp, Hsp, srcS, dstS, t16);
      segsum_k<true><<<(NN + 15) / 16, 256, 0, stream>>>(t16, rowPtr, deg_inv, hacc);
      node_pass<<<NN / 64, 256, 0, stream>>>(hacc, wpm(wp, 14 + l),
                                             nb_ + l * 128, h16);
    }
  }

  out_pass<<<NN / 64, 256, 0, stream>>>(h16, wpm(wp, 17), ob1, oW2, ob2, out);
}

// Round 11
// 633.280 us; speedup vs baseline: 2.9570x; 1.2785x over previous
//
#include <hip/hip_runtime.h>
#include <hip/hip_bf16.h>

#define DEVINL __device__ __forceinline__

typedef float f32x4 __attribute__((ext_vector_type(4)));
typedef unsigned short u16x8 __attribute__((ext_vector_type(8)));
typedef __bf16 bf16x8 __attribute__((ext_vector_type(8)));

static constexpr int NN = 40000;     // nodes
static constexpr int NE = 640000;    // edges (divisible by 256)
static constexpr int H  = 128;
static constexpr int NSCAN = 40;     // ceil(NN/1024)

// ---- ws layout (bytes) ----
static constexpr long O_HACC = 0;                       // f32 [NN][128]
static constexpr long O_H16  = 20480000;                // bf16 [NN][128]
static constexpr long O_DEG  = 30720000;                // f32 [NN] (deg_inv)
static constexpr long O_WP   = 30880000;                // prepped weights 18*32KB
static constexpr long O_HDP  = 31600896;                // bf16 [NN][128] sigma-permuted
static constexpr long O_HSP  = 41840896;                // bf16 [NN][128] sigma-permuted
static constexpr long O_CNT  = 52080896;                // u32 [NN]
static constexpr long O_LOC  = 52240896;                // u32 [NN]
static constexpr long O_ROWP = 52400896;                // u32 [NN+1] (+pad)
static constexpr long O_CURS = 52560912;                // u32 [NN]
static constexpr long O_BSUM = 52720912;                // u32 [64]
static constexpr long O_PERM = 52721168;                // u32 [NE]
static constexpr long O_SRCS = 55281168;                // i32 [NE]
static constexpr long O_DSTS = 57841168;                // i32 [NE]
static constexpr long O_T16  = 60401168;                // (unused; layout kept)
static constexpr long O_EA16 = 224241168;               // bf16 [NE][128] sorted
static constexpr long NEED_T1 = O_EA16;                 // 224.2 MB
static constexpr long NEED_T2 = O_EA16 + (long)NE * H * 2;  // 388.1 MB

// prepped-weight blocks (16384 ushorts each):
// m0 e2n_W1(A)  m1 e2n_W2(K)  m2..10 {W1a,W1b,W1c}(A) per layer
// m11..13 W2(K) per layer     m14..16 nW(A)  m17 outW1(A)
__host__ __device__ inline const unsigned short* wpm(const unsigned short* wp, int m) {
  return wp + m * 16384;
}

DEVINL unsigned short f2bf(float f) {
  unsigned int u = __float_as_uint(f);
  u += 0x7fffu + ((u >> 16) & 1u);     // round-to-nearest-even
  return (unsigned short)(u >> 16);
}
DEVINL float bf2f(unsigned short u) {
  return __uint_as_float(((unsigned int)u) << 16);
}

DEVINL f32x4 mfma16(u16x8 a, u16x8 b, f32x4 c) {
  return __builtin_amdgcn_mfma_f32_16x16x32_bf16(
      __builtin_bit_cast(bf16x8, a), __builtin_bit_cast(bf16x8, b), c, 0, 0, 0);
}

// ---------------- weight prep ----------------
// mode A: Wp[((ks*8+nb)*64+l)*8+j] = W[32ks + 8*(l>>4) + j][16nb + (l&15)]
// mode K: Wp[...]                  = W[4ks + (l>>4) + 16j][16nb + (l&15)]
struct PrepPtrs { const float* p[18]; };

__global__ void prep_all(PrepPtrs pp, unsigned short* __restrict__ wp) {
  constexpr int MODE[18] = {0,1, 0,0,0, 0,0,0, 0,0,0, 1,1,1, 0,0,0, 0};
  int m = blockIdx.y;
  int idx = blockIdx.x * 256 + threadIdx.x;
  if (idx >= 16384) return;
  int j  = idx & 7, l = (idx >> 3) & 63, nb = (idx >> 9) & 7, ks = idx >> 12;
  int hi = l >> 4, lo = l & 15;
  int k = MODE[m] ? (4*ks + hi + 16*j) : (32*ks + 8*hi + j);
  int n = nb*16 + lo;
  wp[m * 16384 + idx] = f2bf(pp.p[m][k*128 + n]);
}

// ---------------- counting sort by dst ----------------
__global__ void hist_k(const int* __restrict__ dst, unsigned* __restrict__ cnt) {
  int e = blockIdx.x * 256 + threadIdx.x;
  atomicAdd(&cnt[dst[e]], 1u);
}

__global__ void scan1_k(const unsigned* __restrict__ cnt, unsigned* __restrict__ loc,
                        unsigned* __restrict__ bsum) {
  __shared__ unsigned sh[256];
  int t = threadIdx.x;
  int base = blockIdx.x * 1024 + t * 4;
  unsigned v[4]; unsigned s = 0;
  #pragma unroll
  for (int j = 0; j < 4; ++j) {
    v[j] = (base + j < NN) ? cnt[base + j] : 0u;
    s += v[j];
  }
  sh[t] = s; __syncthreads();
  #pragma unroll
  for (int off = 1; off < 256; off <<= 1) {
    unsigned y = (t >= off) ? sh[t - off] : 0u;
    __syncthreads();
    sh[t] += y;
    __syncthreads();
  }
  unsigned run = sh[t] - s;   // exclusive base for this thread
  #pragma unroll
  for (int j = 0; j < 4; ++j) {
    if (base + j < NN) loc[base + j] = run;
    run += v[j];
  }
  if (t == 255) bsum[blockIdx.x] = sh[255];
}

__global__ void scan2_k(unsigned* __restrict__ bsum) {
  int t = threadIdx.x;   // 64 threads, one wave
  unsigned orig = (t < NSCAN) ? bsum[t] : 0u;
  unsigned v = orig;
  #pragma unroll
  for (int off = 1; off < 64; off <<= 1) {
    unsigned y = __shfl_up(v, off);
    if (t >= off) v += y;
  }
  if (t < NSCAN) bsum[t] = v - orig;   // exclusive
}

__global__ void scan3_k(const unsigned* __restrict__ loc, const unsigned* __restrict__ bsum,
                        const unsigned* __restrict__ cnt, unsigned* __restrict__ rowPtr,
                        unsigned* __restrict__ cursor, float* __restrict__ deg_inv) {
  int i = blockIdx.x * 256 + threadIdx.x;
  if (i < NN) {
    unsigned r = loc[i] + bsum[i >> 10];
    rowPtr[i] = r;
    cursor[i] = r;
    deg_inv[i] = 1.0f / fmaxf((float)cnt[i], 1.0f);
  }
  if (i == NN) rowPtr[NN] = (unsigned)NE;
}

__global__ void scat_k(const int* __restrict__ src, const int* __restrict__ dst,
                       unsigned* __restrict__ cursor, unsigned* __restrict__ perm,
                       int* __restrict__ srcS, int* __restrict__ dstS) {
  int e = blockIdx.x * 256 + threadIdx.x;
  int d = dst[e];
  unsigned pos = atomicAdd(&cursor[d], 1u);
  perm[pos] = (unsigned)e;
  srcS[pos] = src[e];
  dstS[pos] = d;
}

// ---------------- h0 convert ----------------
__global__ void cvt_h0(const float* __restrict__ src, unsigned short* __restrict__ dst) {
  long i = ((long)blockIdx.x * 256 + threadIdx.x) * 8;
  f32x4 a = *(const f32x4*)(src + i);
  f32x4 b = *(const f32x4*)(src + i + 4);
  u16x8 t;
  #pragma unroll
  for (int j = 0; j < 4; ++j) { t[j] = f2bf(a[j]); t[4+j] = f2bf(b[j]); }
  *(u16x8*)(dst + i) = t;
}

// ---------------- node transform: Hdp = h@W1a, Hsp = h@W1b (sigma-permuted) ----------------
__global__ __launch_bounds__(256) void node_xform(
    const unsigned short* __restrict__ h16,
    const unsigned short* __restrict__ wpa, const unsigned short* __restrict__ wpb,
    unsigned short* __restrict__ Hdp, unsigned short* __restrict__ Hsp) {
  const int tid = threadIdx.x;
  const int wave = tid >> 6, lane = tid & 63;
  const int hi = lane >> 4, lo = lane & 15;
  const int n0w = blockIdx.x * 256 + wave * 64;

  #pragma unroll
  for (int out = 0; out < 2; ++out) {
    const unsigned short* wp = out ? wpb : wpa;
    unsigned short* dp = out ? Hsp : Hdp;
    f32x4 acc[4][8];
    #pragma unroll
    for (int mf = 0; mf < 4; ++mf)
      #pragma unroll
      for (int nb = 0; nb < 8; ++nb) acc[mf][nb] = (f32x4)(0.0f);
    #pragma unroll
    for (int s = 0; s < 4; ++s) {
      u16x8 a[4];
      #pragma unroll
      for (int mf = 0; mf < 4; ++mf) {
        int n = n0w + 16 * mf + lo; if (n >= NN) n = NN - 1;
        a[mf] = *(const u16x8*)(h16 + (long)n * 128 + s * 32 + hi * 8);
      }
      #pragma unroll
      for (int nb = 0; nb < 8; ++nb) {
        u16x8 b = *(const u16x8*)(wp + ((s * 8 + nb) * 64 + lane) * 8);
        #pragma unroll
        for (int mf = 0; mf < 4; ++mf) acc[mf][nb] = mfma16(a[mf], b, acc[mf][nb]);
      }
    }
    #pragma unroll
    for (int mf = 0; mf < 4; ++mf)
      #pragma unroll
      for (int r = 0; r < 4; ++r) {
        int n = n0w + 16 * mf + 4 * hi + r;
        if (n < NN) {
          u16x8 pack;
          #pragma unroll
          for (int nb = 0; nb < 8; ++nb) pack[nb] = f2bf(acc[mf][nb][r]);
          *(u16x8*)(dp + (long)n * 128 + 8 * lo) = pack;   // sigma: col 16nb+lo -> 8lo+nb
        }
      }
  }
}

// ---------------- K12 (fused GEMM1+GEMM2+segment-sum, sorted edges) ----------------
// hacc[dst] += deg_scaled( (relu(ea@W1 [+Hd+Hs] + b1))@W2 + b2 ) summed per dst run.
// Weights LDS-resident; asm-forced load pipeline (R10); seg-sum per wave over the
// m-stripe with boundary atomics only (dst-sorted edges -> ~5 segments / 64 edges).
// vmcnt gate N = LB only (atomic count is data-dependent; over-wait is correct).
// LDS (dynamic 81920): [0,32K) W1; [32K,64K) W2; [64K,80K) 4 wave-stripes.
template<int EAM, bool EAST, bool GATH>
__global__ __launch_bounds__(256, 2) void k12_pass(
    const float* __restrict__ ea32, unsigned short* __restrict__ ea16,
    const unsigned* __restrict__ perm,
    const unsigned short* __restrict__ w1p, const unsigned short* __restrict__ w2p,
    const float* __restrict__ b1, const float* __restrict__ b2,
    const unsigned short* __restrict__ Hdp, const unsigned short* __restrict__ Hsp,
    const int* __restrict__ srcS, const int* __restrict__ dstS,
    const float* __restrict__ deg_inv, float* __restrict__ hacc) {
  extern __shared__ char smem[];
  const int tid = threadIdx.x;
  const int wave = tid >> 6, lane = tid & 63;
  const int hi = lane >> 4, lo = lane & 15;

  // bijective XCD swizzle: contiguous dst-chunk per XCD
  const int nwg = gridDim.x;
  const int xcd = blockIdx.x & 7, bbase = blockIdx.x >> 3;
  const int qc = nwg >> 3, rc = nwg & 7;
  const int bid = (xcd < rc ? xcd * (qc + 1) : rc * (qc + 1) + (xcd - rc) * qc) + bbase;
  const long e0w = (long)bid * 256 + wave * 64;
  char* sstripe = smem + 65536 + wave * 4096;

  constexpr int LB = (EAM == 0 ? 8 : 4) + (GATH ? 8 : 0);   // asm loads / batch

  unsigned pId[4];
  int dId[4], sId[4];
  float dsc[4];
  #pragma unroll
  for (int mf = 0; mf < 4; ++mf) {
    if (EAM == 0) pId[mf] = perm[e0w + 16 * mf + lo];
    dId[mf] = dstS[e0w + 16 * mf + lo];
    if (GATH) {
      sId[mf] = srcS[e0w + 16 * mf + lo];
      dsc[mf] = deg_inv[dId[mf]];
    }
  }

  float b1v[8], b2v[8];
  #pragma unroll
  for (int nb = 0; nb < 8; ++nb) { b1v[nb] = b1[nb * 16 + lo]; b2v[nb] = b2[nb * 16 + lo]; }

  // double-buffered operand sets (asm outputs — tied at the waits, can't be sunk)
  u16x8 eaA[4], eaB[4], gdA[4], gsA[4], gdB[4], gsB[4];
  f32x4 efA[8], efB[8];

  auto issue = [&](int mf, u16x8 (&ea)[4], f32x4 (&ef)[8],
                   u16x8 (&gd)[4], u16x8 (&gs)[4]) {
    if (EAM == 1) {
      #pragma unroll
      for (int s = 0; s < 4; ++s) {
        const unsigned short* p = ea16 + (e0w + 16 * mf + lo) * 128 + s * 32 + hi * 8;
        asm volatile("global_load_dwordx4 %0, %1, off" : "=&v"(ea[s]) : "v"(p) : "memory");
      }
    } else {
      #pragma unroll
      for (int s = 0; s < 4; ++s) {
        const float* p = ea32 + (long)pId[mf] * 128 + s * 32 + hi * 8;
        asm volatile("global_load_dwordx4 %0, %1, off" : "=&v"(ef[2*s])   : "v"(p)     : "memory");
        asm volatile("global_load_dwordx4 %0, %1, off" : "=&v"(ef[2*s+1]) : "v"(p + 4) : "memory");
      }
    }
    if (GATH) {
      #pragma unroll
      for (int r = 0; r < 4; ++r) {
        int rd = __shfl(dId[mf], 4 * hi + r);
        int rs = __shfl(sId[mf], 4 * hi + r);
        const unsigned short* pd = Hdp + (long)rd * 128 + 8 * lo;
        const unsigned short* ps = Hsp + (long)rs * 128 + 8 * lo;
        asm volatile("global_load_dwordx4 %0, %1, off" : "=&v"(gd[r]) : "v"(pd) : "memory");
        asm volatile("global_load_dwordx4 %0, %1, off" : "=&v"(gs[r]) : "v"(ps) : "memory");
      }
    }
  };

  issue(0, eaA, efA, gdA, gsA);   // batch0 lands under weight staging + barrier

  { // stage W1 + W2 into LDS (once)
    const u16x8* g1 = (const u16x8*)w1p;
    u16x8* l1 = (u16x8*)smem;
    #pragma unroll
    for (int i = 0; i < 8; ++i) l1[i * 256 + tid] = g1[i * 256 + tid];
    const u16x8* g2 = (const u16x8*)w2p;
    u16x8* l2 = (u16x8*)(smem + 32768);
    #pragma unroll
    for (int i = 0; i < 8; ++i) l2[i * 256 + tid] = g2[i * 256 + tid];
  }
  __syncthreads();

  // fused segment-sum state: lane owns 2 logical stripe positions -> 2 cols
  float runA = 0.0f, runB = 0.0f, scur = 1.0f;
  int dcur = -1;
  const int cA = 16 * ((2 * lane) & 7) + (lane >> 2);
  const int cB = 16 * ((2 * lane + 1) & 7) + (lane >> 2);

  #pragma unroll
  for (int mf = 0; mf < 4; ++mf) {
    u16x8 (&ea)[4] = (mf & 1) ? eaB : eaA;
    f32x4 (&ef)[8] = (mf & 1) ? efB : efA;
    u16x8 (&gd)[4] = (mf & 1) ? gdB : gdA;
    u16x8 (&gs)[4] = (mf & 1) ? gsB : gsA;
    if (mf < 3)
      issue(mf + 1, (mf & 1) ? eaA : eaB, (mf & 1) ? efA : efB,
            (mf & 1) ? gdA : gdB, (mf & 1) ? gsA : gsB);

    // gate on batch(mf); credit only batch(mf+1) loads (atomics are data-dependent)
    if (EAM == 1) {
      if (GATH) {
        asm volatile("s_waitcnt vmcnt(%12)"
          : "+v"(ea[0]), "+v"(ea[1]), "+v"(ea[2]), "+v"(ea[3]),
            "+v"(gd[0]), "+v"(gd[1]), "+v"(gd[2]), "+v"(gd[3]),
            "+v"(gs[0]), "+v"(gs[1]), "+v"(gs[2]), "+v"(gs[3])
          : "n"(mf < 3 ? LB : 0));
      } else {
        asm volatile("s_waitcnt vmcnt(%4)"
          : "+v"(ea[0]), "+v"(ea[1]), "+v"(ea[2]), "+v"(ea[3])
          : "n"(mf < 3 ? LB : 0));
      }
    } else if (GATH) {
      asm volatile("s_waitcnt vmcnt(%16)"
        : "+v"(ef[0]), "+v"(ef[1]), "+v"(ef[2]), "+v"(ef[3]),
          "+v"(ef[4]), "+v"(ef[5]), "+v"(ef[6]), "+v"(ef[7]),
          "+v"(gd[0]), "+v"(gd[1]), "+v"(gd[2]), "+v"(gd[3]),
          "+v"(gs[0]), "+v"(gs[1]), "+v"(gs[2]), "+v"(gs[3])
        : "n"(mf < 3 ? LB : 0));
    } else {
      asm volatile("s_waitcnt vmcnt(%8)"
        : "+v"(ef[0]), "+v"(ef[1]), "+v"(ef[2]), "+v"(ef[3]),
          "+v"(ef[4]), "+v"(ef[5]), "+v"(ef[6]), "+v"(ef[7])
        : "n"(mf < 3 ? LB : 0));
    }

    if (EAM == 0) {   // convert f32 -> bf16 (and optionally store sorted ea16)
      #pragma unroll
      for (int s = 0; s < 4; ++s) {
        u16x8 t;
        #pragma unroll
        for (int j = 0; j < 4; ++j) { t[j] = f2bf(ef[2*s][j]); t[4+j] = f2bf(ef[2*s+1][j]); }
        if (EAST)
          *(u16x8*)(ea16 + (e0w + 16 * mf + lo) * 128 + s * 32 + hi * 8) = t;
        ea[s] = t;
      }
    }

    // ---- GEMM1 (acc starts at 0; gathers added after) ----
    f32x4 acc[8];
    #pragma unroll
    for (int nb = 0; nb < 8; ++nb) acc[nb] = (f32x4)(0.0f);
    #pragma unroll
    for (int s = 0; s < 4; ++s)
      #pragma unroll
      for (int nb = 0; nb < 8; ++nb) {
        u16x8 b = *(const u16x8*)(smem + ((s * 8 + nb) << 10) + (lane << 4));
        acc[nb] = mfma16(ea[s], b, acc[nb]);
      }
    if (GATH) {
      #pragma unroll
      for (int nb = 0; nb < 8; ++nb)
        #pragma unroll
        for (int r = 0; r < 4; ++r)
          acc[nb][r] += bf2f(gd[r][nb]) + bf2f(gs[r][nb]);
    }

    // ---- epilogue1: bias+relu -> bf16 -> sigma stripe ----
    #pragma unroll
    for (int r = 0; r < 4; ++r) {
      int er = 4 * hi + r;
      u16x8 pack;
      #pragma unroll
      for (int nb = 0; nb < 8; ++nb)
        pack[nb] = f2bf(fmaxf(acc[nb][r] + b1v[nb], 0.0f));
      *(u16x8*)(sstripe + er * 256 + ((lo * 16) ^ ((er & 7) << 4))) = pack;
    }

    // ---- GEMM2 (wave-private stripe, no barrier) ----
    f32x4 acc2[8];
    #pragma unroll
    for (int nb = 0; nb < 8; ++nb) acc2[nb] = (f32x4)(0.0f);
    #pragma unroll
    for (int s2 = 0; s2 < 4; ++s2) {
      u16x8 a = *(const u16x8*)(sstripe + lo * 256 +
                                (((4 * s2 + hi) * 16) ^ ((lo & 7) << 4)));
      #pragma unroll
      for (int nb = 0; nb < 8; ++nb) {
        u16x8 b = *(const u16x8*)(smem + 32768 + ((s2 * 8 + nb) << 10) + (lane << 4));
        acc2[nb] = mfma16(a, b, acc2[nb]);
      }
    }

    // ---- epilogue2: +bias -> bf16 -> stripe (m values, sigma positions) ----
    #pragma unroll
    for (int r = 0; r < 4; ++r) {
      int er = 4 * hi + r;
      u16x8 pack;
      #pragma unroll
      for (int nb = 0; nb < 8; ++nb)
        pack[nb] = f2bf(acc2[nb][r] + b2v[nb]);
      *(u16x8*)(sstripe + er * 256 + ((lo * 16) ^ ((er & 7) << 4))) = pack;
    }

    // ---- fused segment-sum over stripe rows (dst-sorted; wave-uniform runs) ----
    #pragma unroll
    for (int er = 0; er < 16; ++er) {
      int d = __shfl(dId[mf], er);
      float s = GATH ? __shfl(dsc[mf], er) : 1.0f;
      if (d != dcur) {
        if (dcur >= 0) {
          unsafeAtomicAdd(&hacc[(long)dcur * 128 + cA], runA * scur);
          unsafeAtomicAdd(&hacc[(long)dcur * 128 + cB], runB * scur);
        }
        runA = 0.0f; runB = 0.0f; dcur = d; scur = s;
      }
      unsigned pr = *(const unsigned*)(sstripe + er * 256 +
                                       ((lane * 4) ^ ((er & 7) << 4)));
      runA += bf2f((unsigned short)(pr & 0xffffu));
      runB += bf2f((unsigned short)(pr >> 16));
    }
  }
  // final flush
  if (dcur >= 0) {
    unsafeAtomicAdd(&hacc[(long)dcur * 128 + cA], runA * scur);
    unsafeAtomicAdd(&hacc[(long)dcur * 128 + cB], runB * scur);
  }
}

// ---------------- node MLP: h16 = relu(agg @ Wn + bn) ----------------
__global__ __launch_bounds__(256) void node_pass(
    const float* __restrict__ agg, const unsigned short* __restrict__ wp,
    const float* __restrict__ bias, unsigned short* __restrict__ h16out) {
  __shared__ char smem[49152];
  const int tid = threadIdx.x;
  const int wave = tid >> 6, lane = tid & 63;
  const int hi = lane >> 4, lo = lane & 15;
  const int n0 = blockIdx.x * 64;
  const int r = tid >> 2, q = tid & 3;

  #pragma unroll
  for (int s = 0; s < 4; ++s) {
    f32x4 f0 = *(const f32x4*)(agg + (long)(n0 + r) * 128 + s * 32 + q * 8);
    f32x4 f1 = *(const f32x4*)(agg + (long)(n0 + r) * 128 + s * 32 + q * 8 + 4);
    u16x8 t;
    #pragma unroll
    for (int j = 0; j < 4; ++j) { t[j] = f2bf(f0[j]); t[4+j] = f2bf(f1[j]); }
    *(u16x8*)(smem + s * 4096 + (((r >> 4) * 64 + q * 16 + (r & 15)) << 4)) = t;
  }
  {
    const u16x8* g = (const u16x8*)wp;
    u16x8* l = (u16x8*)(smem + 16384);
    #pragma unroll
    for (int i = 0; i < 8; ++i) l[i * 256 + tid] = g[i * 256 + tid];
  }
  __syncthreads();

  f32x4 acc[8];
  #pragma unroll
  for (int nb = 0; nb < 8; ++nb) acc[nb] = (f32x4)(0.0f);
  #pragma unroll
  for (int s = 0; s < 4; ++s) {
    u16x8 a = *(const u16x8*)(smem + s * 4096 + wave * 1024 + (lane << 4));
    #pragma unroll
    for (int nb = 0; nb < 8; ++nb) {
      u16x8 b = *(const u16x8*)(smem + 16384 + ((s * 8 + nb) << 10) + (lane << 4));
      acc[nb] = mfma16(a, b, acc[nb]);
    }
  }
  float bv[8];
  #pragma unroll
  for (int nb = 0; nb < 8; ++nb) bv[nb] = bias[nb * 16 + lo];
  #pragma unroll
  for (int nb = 0; nb < 8; ++nb)
    #pragma unroll
    for (int rr = 0; rr < 4; ++rr) {
      int node = n0 + 16 * wave + 4 * hi + rr;
      float v = fmaxf(acc[nb][rr] + bv[nb], 0.0f);
      h16out[(long)node * 128 + nb * 16 + lo] = f2bf(v);
    }
}

// ---------------- output head ----------------
__global__ __launch_bounds__(256) void out_pass(
    const unsigned short* __restrict__ h16, const unsigned short* __restrict__ wp,
    const float* __restrict__ ob1, const float* __restrict__ oW2,
    const float* __restrict__ ob2, float* __restrict__ out) {
  __shared__ char smem[49152];
  const int tid = threadIdx.x;
  const int wave = tid >> 6, lane = tid & 63;
  const int hi = lane >> 4, lo = lane & 15;
  const int n0 = blockIdx.x * 64;
  const int r = tid >> 2, q = tid & 3;

  #pragma unroll
  for (int s = 0; s < 4; ++s) {
    u16x8 t = *(const u16x8*)(h16 + (long)(n0 + r) * 128 + s * 32 + q * 8);
    *(u16x8*)(smem + s * 4096 + (((r >> 4) * 64 + q * 16 + (r & 15)) << 4)) = t;
  }
  {
    const u16x8* g = (const u16x8*)wp;
    u16x8* l = (u16x8*)(smem + 16384);
    #pragma unroll
    for (int i = 0; i < 8; ++i) l[i * 256 + tid] = g[i * 256 + tid];
  }
  __syncthreads();

  f32x4 acc[8];
  #pragma unroll
  for (int nb = 0; nb < 8; ++nb) acc[nb] = (f32x4)(0.0f);
  #pragma unroll
  for (int s = 0; s < 4; ++s) {
    u16x8 a = *(const u16x8*)(smem + s * 4096 + wave * 1024 + (lane << 4));
    #pragma unroll
    for (int nb = 0; nb < 8; ++nb) {
      u16x8 b = *(const u16x8*)(smem + 16384 + ((s * 8 + nb) << 10) + (lane << 4));
      acc[nb] = mfma16(a, b, acc[nb]);
    }
  }
  float b1v[8], w2v[8][3];
  #pragma unroll
  for (int nb = 0; nb < 8; ++nb) {
    b1v[nb] = ob1[nb * 16 + lo];
    #pragma unroll
    for (int o = 0; o < 3; ++o) w2v[nb][o] = oW2[(nb * 16 + lo) * 3 + o];
  }
  #pragma unroll
  for (int rr = 0; rr < 4; ++rr) {
    float p0 = 0.f, p1 = 0.f, p2 = 0.f;
    #pragma unroll
    for (int nb = 0; nb < 8; ++nb) {
      float t = fmaxf(acc[nb][rr] + b1v[nb], 0.0f);
      p0 += t * w2v[nb][0]; p1 += t * w2v[nb][1]; p2 += t * w2v[nb][2];
    }
    #pragma unroll
    for (int off = 1; off < 16; off <<= 1) {
      p0 += __shfl_xor(p0, off); p1 += __shfl_xor(p1, off); p2 += __shfl_xor(p2, off);
    }
    if (lo == 0) {
      int node = n0 + 16 * wave + 4 * hi + rr;
      out[(long)node * 3 + 0] = p0 + ob2[0];
      out[(long)node * 3 + 1] = p1 + ob2[1];
      out[(long)node * 3 + 2] = p2 + ob2[2];
    }
  }
}

// ---------------- host ----------------
extern "C" void kernel_launch(void* const* d_in, const int* in_sizes, int n_in,
                              void* d_out, int out_size, void* d_ws, size_t ws_size,
                              hipStream_t stream) {
  const int*   ei     = (const int*)d_in[1];
  const int*   srcIds = ei;
  const int*   dstIds = ei + NE;
  const float* ea     = (const float*)d_in[2];
  const float* e2nb1  = (const float*)d_in[4];
  const float* e2nb2  = (const float*)d_in[6];
  const float* eW1    = (const float*)d_in[7];
  const float* eb1    = (const float*)d_in[8];
  const float* eW2    = (const float*)d_in[9];
  const float* eb2    = (const float*)d_in[10];
  const float* nW     = (const float*)d_in[11];
  const float* nb_    = (const float*)d_in[12];
  const float* ob1    = (const float*)d_in[14];
  const float* oW2    = (const float*)d_in[15];
  const float* ob2    = (const float*)d_in[16];
  float* out = (float*)d_out;

  char* ws = (char*)d_ws;
  float* hacc = (float*)(ws + O_HACC);
  unsigned short* h16 = (unsigned short*)(ws + O_H16);
  float* deg_inv = (float*)(ws + O_DEG);
  unsigned short* wp = (unsigned short*)(ws + O_WP);
  unsigned short* Hdp = (unsigned short*)(ws + O_HDP);
  unsigned short* Hsp = (unsigned short*)(ws + O_HSP);
  unsigned* cnt    = (unsigned*)(ws + O_CNT);
  unsigned* loc    = (unsigned*)(ws + O_LOC);
  unsigned* rowPtr = (unsigned*)(ws + O_ROWP);
  unsigned* cursor = (unsigned*)(ws + O_CURS);
  unsigned* bsum   = (unsigned*)(ws + O_BSUM);
  unsigned* perm   = (unsigned*)(ws + O_PERM);
  int* srcS        = (int*)(ws + O_SRCS);
  int* dstS        = (int*)(ws + O_DSTS);
  unsigned short* ea16 = (unsigned short*)(ws + O_EA16);
  const bool tier2 = ws_size >= (size_t)NEED_T2;

  PrepPtrs pp;
  pp.p[0] = (const float*)d_in[3];
  pp.p[1] = (const float*)d_in[5];
  for (int l = 0; l < 3; ++l) {
    pp.p[2 + 3*l] = eW1 + l * 49152;             // W1a
    pp.p[3 + 3*l] = eW1 + l * 49152 + 16384;     // W1b
    pp.p[4 + 3*l] = eW1 + l * 49152 + 32768;     // W1c
    pp.p[11 + l]  = eW2 + l * 16384;             // W2 (kappa)
    pp.p[14 + l]  = nW  + l * 16384;             // nW
  }
  pp.p[17] = (const float*)d_in[13];

  prep_all<<<dim3(64, 18), 256, 0, stream>>>(pp, wp);

  // counting sort by dst + deg_inv
  hipMemsetAsync(cnt, 0, (size_t)NN * 4, stream);
  hist_k<<<NE / 256, 256, 0, stream>>>(dstIds, cnt);
  scan1_k<<<NSCAN, 256, 0, stream>>>(cnt, loc, bsum);
  scan2_k<<<1, 64, 0, stream>>>(bsum);
  scan3_k<<<(NN + 256) / 256, 256, 0, stream>>>(loc, bsum, cnt, rowPtr, cursor, deg_inv);
  scat_k<<<NE / 256, 256, 0, stream>>>(srcIds, dstIds, cursor, perm, srcS, dstS);

  // ---- e2n: fused edge-MLP + scatter-sum into hacc ----
  hipMemsetAsync(hacc, 0, (size_t)NN * H * 4, stream);
  if (tier2)
    k12_pass<0, true, false><<<NE / 256, 256, 81920, stream>>>(
        ea, ea16, perm, wpm(wp, 0), wpm(wp, 1), e2nb1, e2nb2,
        nullptr, nullptr, srcS, dstS, deg_inv, hacc);
  else
    k12_pass<0, false, false><<<NE / 256, 256, 81920, stream>>>(
        ea, nullptr, perm, wpm(wp, 0), wpm(wp, 1), e2nb1, e2nb2,
        nullptr, nullptr, srcS, dstS, deg_inv, hacc);
  cvt_h0<<<NN * H / (256 * 8), 256, 0, stream>>>(hacc, h16);

  for (int l = 0; l < 3; ++l) {
    node_xform<<<(NN + 255) / 256, 256, 0, stream>>>(
        h16, wpm(wp, 2 + 3*l), wpm(wp, 3 + 3*l), Hdp, Hsp);
    hipMemsetAsync(hacc, 0, (size_t)NN * H * 4, stream);
    if (tier2)
      k12_pass<1, false, true><<<NE / 256, 256, 81920, stream>>>(
          ea, ea16, perm, wpm(wp, 4 + 3*l), wpm(wp, 11 + l),
          eb1 + l * 128, eb2 + l * 128, Hdp, Hsp, srcS, dstS, deg_inv, hacc);
    else
      k12_pass<0, false, true><<<NE / 256, 256, 81920, stream>>>(
          ea, nullptr, perm, wpm(wp, 4 + 3*l), wpm(wp, 11 + l),
          eb1 + l * 128, eb2 + l * 128, Hdp, Hsp, srcS, dstS, deg_inv, hacc);
    node_pass<<<NN / 64, 256, 0, stream>>>(hacc, wpm(wp, 14 + l),
                                           nb_ + l * 128, h16);
  }

  out_pass<<<NN / 64, 256, 0, stream>>>(h16, wpm(wp, 17), ob1, oW2, ob2, out);
}